// Round 7
// baseline (341.897 us; speedup 1.0000x reference)
//
#include <hip/hip_runtime.h>
#include <cstdint>
#include <cstddef>

#define NN 100000
#define NE 1600000
#define F  128
#define NPAD 100352          // 98 * 1024
#define NBUCK 3125           // NN / 32 fine buckets of 32 nodes (gather granularity)
#define BCAPG 768            // fine bucket capacity (mean 512, +11 sd)
#define NFILL 1536           // fill blocks (6/CU resident)
#define NGEMM 1024           // gemm blocks (~3 tiles each)
#define NGATH 1563           // gather blocks: 2 buckets each, all co-resident
#define CHUNK 1042           // ceil(NE / NFILL)
#define GSTRIDE 16           // cursor padding: one counter per 64B line
#define NREG 49              // coarse regions (2048 nodes each)
#define RCAP 36864           // region capacity (mean ~32650, +23 sd)
#define P2SPLIT 16           // pass-2 sort blocks per region
#define P2J 17               // + 1 deg-histogram block per region
#define P2MAX 2304           // ceil(RCAP / P2SPLIT)

typedef __attribute__((ext_vector_type(8))) short bf16x8;
typedef __attribute__((ext_vector_type(4))) float f32x4;

// bf16 helpers (RNE)
__device__ __forceinline__ unsigned short f2bf(float f) {
    unsigned u = __float_as_uint(f);
    unsigned r = (u + 0x7fffu + ((u >> 16) & 1u)) >> 16;
    return (unsigned short)r;
}
// add 8 bf16 (packed in uint4) into acc — ns is pre-folded into hs
__device__ __forceinline__ void acc_bf8(const uint4 v, float* acc) {
    acc[0] += __uint_as_float(v.x << 16);
    acc[1] += __uint_as_float(v.x & 0xffff0000u);
    acc[2] += __uint_as_float(v.y << 16);
    acc[3] += __uint_as_float(v.y & 0xffff0000u);
    acc[4] += __uint_as_float(v.z << 16);
    acc[5] += __uint_as_float(v.z & 0xffff0000u);
    acc[6] += __uint_as_float(v.w << 16);
    acc[7] += __uint_as_float(v.w & 0xffff0000u);
}

// ---------------- setup: cursors + head constant + V = W2 @ Wp ----------------
__global__ void setup_kernel(int* __restrict__ gCur, int* __restrict__ gRegCur,
                             int* __restrict__ gRegCurS,
                             const float* __restrict__ W2, const float* __restrict__ Wp,
                             const float* __restrict__ b2, const float* __restrict__ bp,
                             float* __restrict__ consts, float2* __restrict__ V) {
    const int g = blockIdx.x;
    const int tid = threadIdx.x;
    if (g < 13) {                         // 13*256 = 3328 >= NBUCK
        const int b = g * 256 + tid;
        if (b < NBUCK) gCur[b * GSTRIDE] = b * BCAPG;
        return;
    }
    if (g == 14) {                        // region cursors (both streams)
        if (tid < NREG) gRegCur[tid * GSTRIDE] = tid * RCAP;
        else if (tid >= 64 && tid < 64 + NREG) {
            const int r = tid - 64;
            gRegCurS[r * GSTRIDE] = r * RCAP;
        }
        return;
    }
    // block 13: head fold weights + constant
    if (tid < 128) {                      // V[i] = (W2[i]·Wp_a, W2[i]·Wp_c)
        float sa = 0.f, sc = 0.f;
        #pragma unroll 8
        for (int j = 0; j < F; ++j) {
            const float w = W2[tid * F + j];
            sa += w * Wp[j];
            sc += w * Wp[F + j];
        }
        V[tid] = make_float2(sa, sc);
    } else if (tid < 192) {               // wave 2: cc = b2.Wp_a + b2.Wp_c + bp
        const int l = tid - 128;
        const float2 bb = *(const float2*)&b2[2 * l];
        const float2 wa = *(const float2*)&Wp[2 * l];
        const float2 wc = *(const float2*)&Wp[F + 2 * l];
        float s = bb.x * (wa.x + wc.x) + bb.y * (wa.y + wc.y);
        #pragma unroll
        for (int m = 32; m > 0; m >>= 1) s += __shfl_xor(s, m);
        if (l == 0) consts[0] = s + bp[0];
    }
}

// ---------------- pass-1 coarse binning: TWO streams, ZERO per-edge global atomics ----
__global__ __launch_bounds__(256, 8)
void fill_kernel(const int* __restrict__ src, const int* __restrict__ dst,
                 int* __restrict__ gRegCur, int* __restrict__ gRegCurS,
                 int* __restrict__ gRegion, unsigned short* __restrict__ gRegionS) {
    __shared__ int sortedL[CHUNK];
    __shared__ unsigned char regOf[CHUNK];
    __shared__ int cnt[NREG], cur[NREG], base[NREG];

    const int g = blockIdx.x;
    const int tid = threadIdx.x;
    const int e0 = g * CHUNK;
    const int nCh = min(CHUNK, NE - e0);

    // ---- round 1: key = dst >> 11
    if (tid < NREG) cnt[tid] = 0;
    __syncthreads();
    for (int i = tid; i < nCh; i += 256)
        atomicAdd(&cnt[dst[e0 + i] >> 11], 1);
    __syncthreads();
    if (tid < NREG && cnt[tid] > 0)
        base[tid] = atomicAdd(&gRegCur[tid * GSTRIDE], cnt[tid]);
    if (tid == 0) {
        int run = 0;
        for (int r = 0; r < NREG; ++r) { cur[r] = run; run += cnt[r]; }
    }
    __syncthreads();
    for (int i = tid; i < nCh; i += 256) {
        const int s = src[e0 + i];
        const int d = dst[e0 + i];
        const int r = d >> 11;
        const int p = atomicAdd(&cur[r], 1);
        sortedL[p] = s | ((d & 0x7FF) << 17);
        regOf[p] = (unsigned char)r;
    }
    __syncthreads();
    for (int i = tid; i < nCh; i += 256) {
        const int r = regOf[i];
        const int dstAbs = base[r] + (i - (cur[r] - cnt[r]));
        if (dstAbs < (r + 1) * RCAP)
            gRegion[dstAbs] = sortedL[i];
    }
    __syncthreads();

    // ---- round 2: key = src >> 11 (deg stream, u16 payload)
    if (tid < NREG) cnt[tid] = 0;
    __syncthreads();
    for (int i = tid; i < nCh; i += 256)
        atomicAdd(&cnt[src[e0 + i] >> 11], 1);
    __syncthreads();
    if (tid < NREG && cnt[tid] > 0)
        base[tid] = atomicAdd(&gRegCurS[tid * GSTRIDE], cnt[tid]);
    if (tid == 0) {
        int run = 0;
        for (int r = 0; r < NREG; ++r) { cur[r] = run; run += cnt[r]; }
    }
    __syncthreads();
    for (int i = tid; i < nCh; i += 256) {
        const int s = src[e0 + i];
        const int r = s >> 11;
        const int p = atomicAdd(&cur[r], 1);
        sortedL[p] = s;
        regOf[p] = (unsigned char)r;
    }
    __syncthreads();
    for (int i = tid; i < nCh; i += 256) {
        const int r = regOf[i];
        const int dstAbs = base[r] + (i - (cur[r] - cnt[r]));
        if (dstAbs < (r + 1) * RCAP)
            gRegionS[dstAbs] = (unsigned short)(sortedL[i] & 0x7FF);
    }
}

// ---------------- gemm1 (MFMA, B-in-registers) + norm_src pre-multiply ----------------
// hs_bf[n][:] = bf16(norm_src[n] * (x[n][:] @ W1)) — folding ns here removes the
// 1.6M per-edge norm_src loads + multiplies from the gather hot loop.
__global__ __launch_bounds__(256, 4)
void gemm1_kernel(const float* __restrict__ in, const float* __restrict__ W,
                  const float* __restrict__ norm_src,
                  unsigned short* __restrict__ out_bf) {
    __shared__ __align__(16) char A_s[8192];    // fragment-ordered A tile (bf16)

    const int g    = blockIdx.x;
    const int tid  = threadIdx.x;
    const int w    = tid >> 6;          // wave 0..3 -> cols 32w..32w+31
    const int lane = tid & 63;
    const int ml   = lane & 15;
    const int quad = lane >> 4;

    bf16x8 Bf[4][2];
    #pragma unroll
    for (int kb = 0; kb < 4; ++kb) {
        #pragma unroll
        for (int nb = 0; nb < 2; ++nb) {
            const int n = 32 * w + nb * 16 + ml;
            const int k0 = kb * 32 + quad * 8;
            #pragma unroll
            for (int j = 0; j < 8; ++j)
                Bf[kb][nb][j] = (short)f2bf(W[(k0 + j) * F + n]);
        }
    }

    const int nTiles = NN / 32;                     // 3125
    for (int tile = g; tile < nTiles; tile += NGEMM) {
        const int row0 = tile * 32;
        __syncthreads();
        #pragma unroll
        for (int c = 0; c < 2; ++c) {
            const int i2 = tid + 256 * c;           // 0..511
            const int m  = i2 >> 4;                 // row 0..31
            const int o  = i2 & 15;                 // k-octet
            const float* xr = &in[(size_t)(row0 + m) * F + o * 8];
            const float4 v0 = *(const float4*)xr;
            const float4 v1 = *(const float4*)(xr + 4);
            short h8[8];
            h8[0] = (short)f2bf(v0.x); h8[1] = (short)f2bf(v0.y);
            h8[2] = (short)f2bf(v0.z); h8[3] = (short)f2bf(v0.w);
            h8[4] = (short)f2bf(v1.x); h8[5] = (short)f2bf(v1.y);
            h8[6] = (short)f2bf(v1.z); h8[7] = (short)f2bf(v1.w);
            const int kb2 = o >> 2, q2 = o & 3, ml2 = m & 15, mh2 = m >> 4;
            const int fo = (((mh2 * 4 + kb2) * 64) + q2 * 16 + ml2) * 16;
            *(bf16x8*)(A_s + fo) = *(bf16x8*)h8;
        }
        __syncthreads();

        f32x4 acc00 = {0,0,0,0}, acc01 = {0,0,0,0}, acc10 = {0,0,0,0}, acc11 = {0,0,0,0};
        #pragma unroll
        for (int kb = 0; kb < 4; ++kb) {
            const bf16x8 ah0 = *(const bf16x8*)(A_s + (kb * 64 + lane) * 16);
            const bf16x8 ah1 = *(const bf16x8*)(A_s + ((4 + kb) * 64 + lane) * 16);
            acc00 = __builtin_amdgcn_mfma_f32_16x16x32_bf16(ah0, Bf[kb][0], acc00, 0, 0, 0);
            acc01 = __builtin_amdgcn_mfma_f32_16x16x32_bf16(ah0, Bf[kb][1], acc01, 0, 0, 0);
            acc10 = __builtin_amdgcn_mfma_f32_16x16x32_bf16(ah1, Bf[kb][0], acc10, 0, 0, 0);
            acc11 = __builtin_amdgcn_mfma_f32_16x16x32_bf16(ah1, Bf[kb][1], acc11, 0, 0, 0);
        }

        // epilogue: C/D layout col=lane&15, row=quad*4+reg; scale rows by norm_src
        #pragma unroll
        for (int mh = 0; mh < 2; ++mh) {
            const int rowb = row0 + mh * 16 + quad * 4;
            float ns[4];
            #pragma unroll
            for (int r = 0; r < 4; ++r) ns[r] = norm_src[rowb + r];
            #pragma unroll
            for (int nb = 0; nb < 2; ++nb) {
                const f32x4 a = (mh == 0) ? (nb == 0 ? acc00 : acc01)
                                          : (nb == 0 ? acc10 : acc11);
                const int col = 32 * w + nb * 16 + ml;
                #pragma unroll
                for (int r = 0; r < 4; ++r)
                    out_bf[(size_t)(rowb + r) * F + col] = f2bf(a[r] * ns[r]);
            }
        }
    }
}

// ---------------- pass 2: region -> fine buckets; + per-region deg histogram ----------------
__global__ __launch_bounds__(256)
void pass2_kernel(const int* __restrict__ gRegion, const unsigned short* __restrict__ gRegionS,
                  const int* __restrict__ gRegCur, const int* __restrict__ gRegCurS,
                  int* __restrict__ gCur, int* __restrict__ srcPart,
                  float* __restrict__ norm_src) {
    __shared__ __align__(16) char smem[12544];

    const int r   = blockIdx.x / P2J;
    const int j   = blockIdx.x % P2J;
    const int tid = threadIdx.x;

    if (j == P2SPLIT) {                       // ---- deg role: src histogram
        int* hist = (int*)smem;               // 2048 ints
        const int total = min(gRegCurS[r * GSTRIDE] - r * RCAP, RCAP);
        for (int t = tid; t < 2048; t += 256) hist[t] = 0;
        __syncthreads();
        for (int i = tid; i < total; i += 256)
            atomicAdd(&hist[gRegionS[r * RCAP + i]], 1);
        __syncthreads();
        const int nlo = r * 2048;
        for (int t = tid; t < 2048; t += 256) {
            const int n = nlo + t;
            if (n < NN) norm_src[n] = rsqrtf((float)max(hist[t], 1));
        }
        return;
    }

    // ---- sort role
    int* sortedL = (int*)smem;                              // P2MAX ints (9216 B)
    unsigned char* fbOf = (unsigned char*)(smem + 9216);    // P2MAX u8 (2304 B)
    int* cnt  = (int*)(smem + 11520);                       // 64 ints
    int* cur  = cnt + 64;
    int* base = cur + 64;

    const int total = min(gRegCur[r * GSTRIDE] - r * RCAP, RCAP);
    const int per = (total + P2SPLIT - 1) / P2SPLIT;
    const int i0 = j * per;
    const int i1 = min(total, i0 + per);
    const int n = i1 - i0;                       // may be <= 0 for tail blocks

    if (tid < 64) cnt[tid] = 0;
    __syncthreads();

    int v[9];                                    // ceil(P2MAX/256) = 9
    #pragma unroll
    for (int k = 0; k < 9; ++k) {
        const int i = tid + k * 256;
        if (i < n) {
            const int vv = gRegion[r * RCAP + i0 + i];
            v[k] = vv;
            atomicAdd(&cnt[vv >> 22], 1);        // fb = (d&0x7FF)>>5
        }
    }
    __syncthreads();
    if (tid < 64 && cnt[tid] > 0)
        base[tid] = atomicAdd(&gCur[(r * 64 + tid) * GSTRIDE], cnt[tid]);
    if (tid == 0) {
        int run = 0;
        for (int f = 0; f < 64; ++f) { cur[f] = run; run += cnt[f]; }
    }
    __syncthreads();
    #pragma unroll
    for (int k = 0; k < 9; ++k) {
        const int i = tid + k * 256;
        if (i < n) {
            const int fb = v[k] >> 22;
            const int p = atomicAdd(&cur[fb], 1);
            sortedL[p] = v[k] & 0x3FFFFF;        // s | ((d&31)<<17)
            fbOf[p] = (unsigned char)fb;
        }
    }
    __syncthreads();
    for (int i = tid; i < n; i += 256) {
        const int fb = fbOf[i];
        const int dstAbs = base[fb] + (i - (cur[fb] - cnt[fb]));
        if (dstAbs < (r * 64 + fb + 1) * BCAPG)
            srcPart[dstAbs] = sortedL[i];
    }
}

// ---------------- gather + per-bucket LDS counting sort + fused layer-2 head fold ----------------
// Persistent: 1563 blocks x 2 buckets — single fully-resident round, no tail.
// hs rows are pre-scaled by norm_src -> hot loop is pure 16B loads + adds.
__global__ __launch_bounds__(256)
void gather_sort_kernel(const unsigned short* __restrict__ hs,
                        int* __restrict__ srcPart, const int* __restrict__ gCur,
                        const float* __restrict__ norm_src, const float* __restrict__ bias,
                        const float2* __restrict__ V, float2* __restrict__ uw,
                        int* __restrict__ offs, int* __restrict__ ends,
                        float* __restrict__ norm_dst) {
    __shared__ int cnt[32];
    __shared__ int loc[32];       // inclusive prefix
    __shared__ int cur[32];
    __shared__ int sortedL[BCAPG];

    const int tid = threadIdx.x;
    const int w  = tid >> 6;
    const int l  = tid & 63;
    const int q  = l >> 4;
    const int c8 = (l & 15) * 8;
    float bb[8];
    *(float4*)&bb[0] = *(const float4*)&bias[c8];
    *(float4*)&bb[4] = *(const float4*)&bias[c8 + 4];
    float2 Vl[8];
    #pragma unroll
    for (int k = 0; k < 8; ++k) Vl[k] = V[c8 + k];

    for (int b = blockIdx.x; b < NBUCK; b += NGATH) {
        __syncthreads();              // protect LDS reuse across bucket iterations
        const int nlo = b * 32;
        const int nCnt = min(32, NN - nlo);
        const int eBase = b * BCAPG;
        const int total = min(gCur[b * GSTRIDE] - eBase, BCAPG);

        if (tid < 32) cnt[tid] = 0;
        __syncthreads();
        for (int i = tid; i < total; i += 256)
            atomicAdd(&cnt[(srcPart[eBase + i] >> 17) & 31], 1);
        __syncthreads();
        if (tid < 32) loc[tid] = cnt[tid];
        __syncthreads();
        for (int off = 1; off < 32; off <<= 1) {
            int v = 0;
            if (tid < 32 && tid >= off) v = loc[tid - off];
            __syncthreads();
            if (tid < 32) loc[tid] += v;
            __syncthreads();
        }
        if (tid < 32) cur[tid] = loc[tid] - cnt[tid];
        if (tid < nCnt) {
            const int st = eBase + loc[tid] - cnt[tid];
            offs[nlo + tid] = st;
            ends[nlo + tid] = st + cnt[tid];
            norm_dst[nlo + tid] = rsqrtf((float)max(cnt[tid], 1));
        }
        __syncthreads();
        for (int i = tid; i < total; i += 256) {
            const int v = srcPart[eBase + i];
            const int r = atomicAdd(&cur[(v >> 17) & 31], 1);
            sortedL[r] = v & 0x1FFFF;
        }
        __syncthreads();
        for (int i = tid; i < total; i += 256)
            srcPart[eBase + i] = sortedL[i];

        // ---- feature gather (per wave: 8 nodes; 16 lanes per edge, 8 bf16 cols/lane)
        const int nhEnd = min((w + 1) * 8, nCnt);
        for (int nh = w * 8; nh < nhEnd; ++nh) {
            const int end = loc[nh];
            const int beg = end - cnt[nh];
            float acc[8] = {0.f, 0.f, 0.f, 0.f, 0.f, 0.f, 0.f, 0.f};
            int j = beg;
            for (; j + 16 <= end; j += 16) {      // 16 edges in flight per wave
                const int s0 = sortedL[j + q];
                const int s1 = sortedL[j + 4 + q];
                const int s2 = sortedL[j + 8 + q];
                const int s3 = sortedL[j + 12 + q];
                const uint4 v0 = *(const uint4*)&hs[(size_t)s0 * F + c8];
                const uint4 v1 = *(const uint4*)&hs[(size_t)s1 * F + c8];
                const uint4 v2 = *(const uint4*)&hs[(size_t)s2 * F + c8];
                const uint4 v3 = *(const uint4*)&hs[(size_t)s3 * F + c8];
                acc_bf8(v0, acc);
                acc_bf8(v1, acc);
                acc_bf8(v2, acc);
                acc_bf8(v3, acc);
            }
            for (; j + 8 <= end; j += 8) {
                const int s0 = sortedL[j + q];
                const int s1 = sortedL[j + 4 + q];
                const uint4 v0 = *(const uint4*)&hs[(size_t)s0 * F + c8];
                const uint4 v1 = *(const uint4*)&hs[(size_t)s1 * F + c8];
                acc_bf8(v0, acc);
                acc_bf8(v1, acc);
            }
            for (; j + 4 <= end; j += 4) {
                const int s = sortedL[j + q];
                const uint4 v = *(const uint4*)&hs[(size_t)s * F + c8];
                acc_bf8(v, acc);
            }
            if (j + q < end) {
                const int s = sortedL[j + q];
                const uint4 v = *(const uint4*)&hs[(size_t)s * F + c8];
                acc_bf8(v, acc);
            }
            #pragma unroll
            for (int k = 0; k < 8; ++k) {
                acc[k] += __shfl_xor(acc[k], 16);
                acc[k] += __shfl_xor(acc[k], 32);
            }

            const int n = nlo + nh;
            const float nd = rsqrtf((float)max(cnt[nh], 1));
            float pa = 0.f, pc = 0.f;
            #pragma unroll
            for (int k = 0; k < 8; ++k) {
                const float ok = fmaxf(acc[k] * nd + bb[k], 0.f);
                pa += ok * Vl[k].x;
                pc += ok * Vl[k].y;
            }
            #pragma unroll
            for (int m = 1; m <= 8; m <<= 1) {
                pa += __shfl_xor(pa, m);
                pc += __shfl_xor(pc, m);
            }
            if (l == 0) {
                const float ns = norm_src[n];
                uw[n] = make_float2(ns * pa, ns * pc);
            }
        }
    }
}

// ---------------- layer-2 scalar aggregation ----------------
__global__ void ac_kernel(const float2* __restrict__ uw, const int* __restrict__ sorted_src,
                          const int* __restrict__ offs, const int* __restrict__ ends,
                          const float* __restrict__ norm_dst,
                          float* __restrict__ A, float* __restrict__ C, int nN) {
    const int n = blockIdx.x * blockDim.x + threadIdx.x;
    if (n >= nN) return;
    const int beg = offs[n];
    const int end = ends[n];
    float su = 0.f, sw = 0.f;
    int j = beg;
    for (; j + 2 <= end; j += 2) {
        const float2 t0 = uw[sorted_src[j]];
        const float2 t1 = uw[sorted_src[j + 1]];
        su += t0.x + t1.x;
        sw += t0.y + t1.y;
    }
    if (j < end) {
        const float2 t = uw[sorted_src[j]];
        su += t.x;
        sw += t.y;
    }
    const float nd = norm_dst[n];
    A[n] = nd * su;
    C[n] = nd * sw;
}

// ---------------- edge scores (4-wide) ----------------
__global__ void score_kernel(const float* __restrict__ A, const float* __restrict__ C,
                             const int4* __restrict__ src4, const int4* __restrict__ dst4,
                             const float* __restrict__ consts, float4* __restrict__ out4,
                             int nE4) {
    const int i = blockIdx.x * blockDim.x + threadIdx.x;
    if (i < nE4) {
        const int4 s = src4[i];
        const int4 d = dst4[i];
        const float cc = consts[0];
        float4 o;
        o.x = 1.f / (1.f + __expf(-(A[s.x] + C[d.x] + cc)));
        o.y = 1.f / (1.f + __expf(-(A[s.y] + C[d.y] + cc)));
        o.z = 1.f / (1.f + __expf(-(A[s.z] + C[d.z] + cc)));
        o.w = 1.f / (1.f + __expf(-(A[s.w] + C[d.w] + cc)));
        out4[i] = o;
    }
}

extern "C" void kernel_launch(void* const* d_in, const int* in_sizes, int n_in,
                              void* d_out, int out_size, void* d_ws, size_t ws_size,
                              hipStream_t stream) {
    const float* x  = (const float*)d_in[0];
    const float* W1 = (const float*)d_in[1];
    const float* b1 = (const float*)d_in[2];
    const float* W2 = (const float*)d_in[3];
    const float* b2 = (const float*)d_in[4];
    const float* Wp = (const float*)d_in[5];
    const float* bp = (const float*)d_in[6];
    const int*   src = (const int*)d_in[7];
    const int*   dst = (const int*)d_in[8];
    float* out = (float*)d_out;

    float* ws        = (float*)d_ws;
    float* norm_src  = ws;                        // NPAD
    float* bufA      = ws + NPAD;                 // NPAD: A[]
    float* bufC      = ws + 2 * NPAD;             // NPAD: C[]
    float* norm_dst  = ws + 3 * NPAD;             // NPAD
    int*   offs      = (int*)(ws + 4 * NPAD);     // NPAD
    int*   ends      = offs + NPAD;               // NPAD
    int*   gCur      = ends + NPAD;               // NBUCK*GSTRIDE = 50000, pad 50176
    int*   gRegCur   = gCur + 50176;              // NREG*GSTRIDE = 784, pad 1024
    int*   gRegCurS  = gRegCur + 1024;            // NREG*GSTRIDE = 784, pad 1024
    float* consts    = (float*)(gRegCurS + 1024); // 16
    float2* V        = (float2*)(consts + 16);    // 128 float2
    float2* uw       = V + 128;                   // NN float2
    int*   srcPart   = (int*)(uw + NN);           // NBUCK*BCAPG ints (9.6 MB)
    unsigned short* hs_bf = (unsigned short*)(srcPart + (size_t)NBUCK * BCAPG);  // NN*F bf16
    int*   gRegion   = (int*)(hs_bf + (size_t)NN * F);          // NREG*RCAP ints (7.2 MB)
    unsigned short* gRegionS = (unsigned short*)(gRegion + (size_t)NREG * RCAP); // NREG*RCAP u16 (3.6 MB)

    // cursors + folded head weights
    setup_kernel<<<15, 256, 0, stream>>>(gCur, gRegCur, gRegCurS, W2, Wp, b2, bp, consts, V);

    // pass-1: coarse binning of both streams (no per-edge global atomics)
    fill_kernel<<<NFILL, 256, 0, stream>>>(src, dst, gRegCur, gRegCurS, gRegion, gRegionS);

    // pass-2: regions -> fine 32-node buckets (coalesced) + per-region deg histogram -> norm_src
    pass2_kernel<<<NREG * P2J, 256, 0, stream>>>(gRegion, gRegionS, gRegCur, gRegCurS,
                                                 gCur, srcPart, norm_src);

    // layer-1 MFMA GEMM with norm_src folded into the bf16 output
    gemm1_kernel<<<NGEMM, 256, 0, stream>>>(x, W1, norm_src, hs_bf);

    // per-bucket LDS sort + feature gather + folded layer-2 head -> uw, offs/ends, norm_dst
    gather_sort_kernel<<<NGATH, 256, 0, stream>>>(hs_bf, srcPart, gCur, norm_src, b1,
                                                  V, uw, offs, ends, norm_dst);

    // layer-2 aggregation collapsed to scalar sums
    ac_kernel<<<(NN + 255) / 256, 256, 0, stream>>>(uw, srcPart, offs, ends, norm_dst,
                                                    bufA, bufC, NN);

    // edge scores (NE divisible by 4)
    score_kernel<<<(NE / 4 + 255) / 256, 256, 0, stream>>>(bufA, bufC, (const int4*)src,
                                                           (const int4*)dst, consts,
                                                           (float4*)out, NE / 4);
}

// Round 8
// 310.121 us; speedup vs baseline: 1.1025x; 1.1025x over previous
//
#include <hip/hip_runtime.h>
#include <cstdint>
#include <cstddef>

#define NN 100000
#define NE 1600000
#define F  128
#define NPAD 100352          // 98 * 1024
#define NBUCK 3125           // NN / 32 fine buckets of 32 nodes (gather granularity)
#define BCAPG 768            // fine bucket capacity (mean 512, +11 sd)
#define CHUNK 4167           // ceil(NE / 384) fill chunks
#define GSTRIDE 16           // cursor padding: one counter per 64B line
#define NREG 49              // coarse regions by d>>11 (2048 nodes each)
#define RCAP 36864           // region capacity (mean ~32650, +23 sd)
#define P2SPLIT 16           // pass-2 blocks per region
#define P2MAX 2304           // ceil(RCAP / P2SPLIT)

typedef __attribute__((ext_vector_type(8))) short bf16x8;
typedef __attribute__((ext_vector_type(4))) float f32x4;

// bf16 helpers (RNE)
__device__ __forceinline__ unsigned short f2bf(float f) {
    unsigned u = __float_as_uint(f);
    unsigned r = (u + 0x7fffu + ((u >> 16) & 1u)) >> 16;
    return (unsigned short)r;
}
__device__ __forceinline__ void acc_bf8s(const uint4 v, const float ns, float* acc) {
    acc[0] += __uint_as_float(v.x << 16) * ns;
    acc[1] += __uint_as_float(v.x & 0xffff0000u) * ns;
    acc[2] += __uint_as_float(v.y << 16) * ns;
    acc[3] += __uint_as_float(v.y & 0xffff0000u) * ns;
    acc[4] += __uint_as_float(v.z << 16) * ns;
    acc[5] += __uint_as_float(v.z & 0xffff0000u) * ns;
    acc[6] += __uint_as_float(v.w << 16) * ns;
    acc[7] += __uint_as_float(v.w & 0xffff0000u) * ns;
}

// ---------------- setup: cursors + head constant + V = W2 @ Wp ----------------
__global__ void setup_kernel(int* __restrict__ gCur, int* __restrict__ gRegCur,
                             const float* __restrict__ W2, const float* __restrict__ Wp,
                             const float* __restrict__ b2, const float* __restrict__ bp,
                             float* __restrict__ consts, float2* __restrict__ V) {
    const int g = blockIdx.x;
    const int tid = threadIdx.x;
    if (g < 13) {                         // 13*256 = 3328 >= NBUCK
        const int b = g * 256 + tid;
        if (b < NBUCK) gCur[b * GSTRIDE] = b * BCAPG;
        return;
    }
    // block 13: head fold weights + constant + region cursors
    if (tid < 128) {                      // V[i] = (W2[i]·Wp_a, W2[i]·Wp_c)
        float sa = 0.f, sc = 0.f;
        #pragma unroll 8
        for (int j = 0; j < F; ++j) {
            const float w = W2[tid * F + j];
            sa += w * Wp[j];
            sc += w * Wp[F + j];
        }
        V[tid] = make_float2(sa, sc);
    } else if (tid < 192) {               // wave 2: cc = b2.Wp_a + b2.Wp_c + bp
        const int l = tid - 128;
        const float2 bb = *(const float2*)&b2[2 * l];
        const float2 wa = *(const float2*)&Wp[2 * l];
        const float2 wc = *(const float2*)&Wp[F + 2 * l];
        float s = bb.x * (wa.x + wc.x) + bb.y * (wa.y + wc.y);
        #pragma unroll
        for (int m = 32; m > 0; m >>= 1) s += __shfl_xor(s, m);
        if (l == 0) consts[0] = s + bp[0];
    } else if (tid < 192 + NREG) {        // wave 3: region cursors
        const int r = tid - 192;
        gRegCur[r * GSTRIDE] = r * RCAP;
    }
}

// ---------------- fused gemm1 (MFMA) + pass-1 coarse binning [round-3 proven] ----------------
// blockIdx%2==1 -> fill role: LDS counting sort by 49 coarse regions (d>>11),
//   claimed contiguous runs (~85 ints) -> COALESCED region scatter. + deg_out atomics.
// blockIdx%2==0 -> gemm role: hs_bf[n][:] = bf16(x[n][:] @ W1), 32x128 MFMA tiles.
__global__ __launch_bounds__(256, 3)
void gemm1_fill_kernel(const float* __restrict__ in, const float* __restrict__ W,
                       unsigned short* __restrict__ out_bf,
                       const int* __restrict__ src, const int* __restrict__ dst,
                       int* __restrict__ deg_out, int* __restrict__ gRegCur,
                       int* __restrict__ gRegion) {
    __shared__ __align__(16) char smem[21504];

    const int g = blockIdx.x;
    const int tid = threadIdx.x;

    if (g & 1) {                                    // ---- fill role (384 blocks)
        int* sortedL = (int*)smem;                          // CHUNK ints   (16668 B)
        unsigned char* regOf = (unsigned char*)(sortedL + CHUNK);  // CHUNK u8 (4167 B)
        int* cnt  = (int*)(smem + 20840);                   // NREG ints
        int* cur  = cnt + NREG;                             // NREG ints
        int* base = cur + NREG;                             // NREG ints

        const int e0 = (g >> 1) * CHUNK;
        const int nCh = min(CHUNK, NE - e0);
        if (tid < NREG) cnt[tid] = 0;
        __syncthreads();
        for (int i = tid; i < nCh; i += 256) {
            const int s = src[e0 + i];
            const int d = dst[e0 + i];
            atomicAdd(&deg_out[s], 1);
            atomicAdd(&cnt[d >> 11], 1);
        }
        __syncthreads();
        if (tid < NREG && cnt[tid] > 0)
            base[tid] = atomicAdd(&gRegCur[tid * GSTRIDE], cnt[tid]);
        if (tid == 0) {
            int run = 0;
            for (int r = 0; r < NREG; ++r) { cur[r] = run; run += cnt[r]; }
        }
        __syncthreads();
        // place into LDS grouped by region (src/dst re-read: L1/L2-hot)
        for (int i = tid; i < nCh; i += 256) {
            const int s = src[e0 + i];
            const int d = dst[e0 + i];
            const int r = d >> 11;
            const int p = atomicAdd(&cur[r], 1);
            sortedL[p] = s | ((d & 0x7FF) << 17);
            regOf[p] = (unsigned char)r;
        }
        __syncthreads();
        // coalesced copy-out: contiguous runs per region
        for (int i = tid; i < nCh; i += 256) {
            const int r = regOf[i];
            const int start = cur[r] - cnt[r];          // cur advanced to end
            const int dstAbs = base[r] + (i - start);
            if (dstAbs < (r + 1) * RCAP)
                gRegion[dstAbs] = sortedL[i];
        }
        return;
    }

    // ---- gemm role (384 blocks), tile = 32 rows x 128 cols
    char* A_s = smem;                   // 8 KB fragment-ordered A tile (bf16)

    const int gid  = g >> 1;
    const int w    = tid >> 6;          // wave 0..3 -> cols 32w..32w+31
    const int lane = tid & 63;
    const int ml   = lane & 15;
    const int quad = lane >> 4;

    // preload B frags once: Bf[kb][nb], j: bf16(W[(kb*32+quad*8+j)*F + 32w+nb*16+ml])
    bf16x8 Bf[4][2];
    #pragma unroll
    for (int kb = 0; kb < 4; ++kb) {
        #pragma unroll
        for (int nb = 0; nb < 2; ++nb) {
            const int n = 32 * w + nb * 16 + ml;
            const int k0 = kb * 32 + quad * 8;
            #pragma unroll
            for (int j = 0; j < 8; ++j)
                Bf[kb][nb][j] = (short)f2bf(W[(k0 + j) * F + n]);
        }
    }

    const int nTiles = NN / 32;                     // 3125
    for (int tile = gid; tile < nTiles; tile += 384) {
        const int row0 = tile * 32;
        __syncthreads();
        // stage A tile in fragment order: 512 chunks of 8 floats -> bf16
        #pragma unroll
        for (int c = 0; c < 2; ++c) {
            const int i2 = tid + 256 * c;           // 0..511
            const int m  = i2 >> 4;                 // row 0..31
            const int o  = i2 & 15;                 // k-octet
            const float* xr = &in[(size_t)(row0 + m) * F + o * 8];
            const float4 v0 = *(const float4*)xr;
            const float4 v1 = *(const float4*)(xr + 4);
            short h8[8];
            h8[0] = (short)f2bf(v0.x); h8[1] = (short)f2bf(v0.y);
            h8[2] = (short)f2bf(v0.z); h8[3] = (short)f2bf(v0.w);
            h8[4] = (short)f2bf(v1.x); h8[5] = (short)f2bf(v1.y);
            h8[6] = (short)f2bf(v1.z); h8[7] = (short)f2bf(v1.w);
            const int kb2 = o >> 2, q2 = o & 3, ml2 = m & 15, mh2 = m >> 4;
            const int fo = (((mh2 * 4 + kb2) * 64) + q2 * 16 + ml2) * 16;
            *(bf16x8*)(A_s + fo) = *(bf16x8*)h8;
        }
        __syncthreads();

        f32x4 acc00 = {0,0,0,0}, acc01 = {0,0,0,0}, acc10 = {0,0,0,0}, acc11 = {0,0,0,0};
        #pragma unroll
        for (int kb = 0; kb < 4; ++kb) {
            const bf16x8 ah0 = *(const bf16x8*)(A_s + (kb * 64 + lane) * 16);
            const bf16x8 ah1 = *(const bf16x8*)(A_s + ((4 + kb) * 64 + lane) * 16);
            acc00 = __builtin_amdgcn_mfma_f32_16x16x32_bf16(ah0, Bf[kb][0], acc00, 0, 0, 0);
            acc01 = __builtin_amdgcn_mfma_f32_16x16x32_bf16(ah0, Bf[kb][1], acc01, 0, 0, 0);
            acc10 = __builtin_amdgcn_mfma_f32_16x16x32_bf16(ah1, Bf[kb][0], acc10, 0, 0, 0);
            acc11 = __builtin_amdgcn_mfma_f32_16x16x32_bf16(ah1, Bf[kb][1], acc11, 0, 0, 0);
        }

        // epilogue: C/D layout col=lane&15, row=quad*4+reg
        #pragma unroll
        for (int mh = 0; mh < 2; ++mh) {
            #pragma unroll
            for (int nb = 0; nb < 2; ++nb) {
                const f32x4 a = (mh == 0) ? (nb == 0 ? acc00 : acc01)
                                          : (nb == 0 ? acc10 : acc11);
                const int row = row0 + mh * 16 + quad * 4;
                const int col = 32 * w + nb * 16 + ml;
                #pragma unroll
                for (int r = 0; r < 4; ++r)
                    out_bf[(size_t)(row + r) * F + col] = f2bf(a[r]);
            }
        }
    }
}

// ---------------- pass 2: coarse region -> fine 32-node buckets (coalesced) ----------------
__global__ __launch_bounds__(256)
void pass2_kernel(const int* __restrict__ gRegion, const int* __restrict__ gRegCur,
                  int* __restrict__ gCur, int* __restrict__ srcPart) {
    __shared__ int sortedL[P2MAX];
    __shared__ unsigned char fbOf[P2MAX];
    __shared__ int cnt[64], cur[64], base[64];

    const int r   = blockIdx.x / P2SPLIT;
    const int j   = blockIdx.x % P2SPLIT;
    const int tid = threadIdx.x;

    const int total = min(gRegCur[r * GSTRIDE] - r * RCAP, RCAP);
    const int per = (total + P2SPLIT - 1) / P2SPLIT;
    const int i0 = j * per;
    const int i1 = min(total, i0 + per);
    const int n = i1 - i0;                       // may be <= 0 for tail blocks

    if (tid < 64) cnt[tid] = 0;
    __syncthreads();

    int v[9];                                    // ceil(P2MAX/256) = 9
    #pragma unroll
    for (int k = 0; k < 9; ++k) {
        const int i = tid + k * 256;
        if (i < n) {
            const int vv = gRegion[r * RCAP + i0 + i];
            v[k] = vv;
            atomicAdd(&cnt[vv >> 22], 1);        // fb = (d&0x7FF)>>5
        }
    }
    __syncthreads();
    if (tid < 64 && cnt[tid] > 0)
        base[tid] = atomicAdd(&gCur[(r * 64 + tid) * GSTRIDE], cnt[tid]);
    if (tid == 0) {
        int run = 0;
        for (int f = 0; f < 64; ++f) { cur[f] = run; run += cnt[f]; }
    }
    __syncthreads();
    #pragma unroll
    for (int k = 0; k < 9; ++k) {
        const int i = tid + k * 256;
        if (i < n) {
            const int fb = v[k] >> 22;
            const int p = atomicAdd(&cur[fb], 1);
            sortedL[p] = v[k] & 0x3FFFFF;        // s | ((d&31)<<17)
            fbOf[p] = (unsigned char)fb;
        }
    }
    __syncthreads();
    for (int i = tid; i < n; i += 256) {
        const int fb = fbOf[i];
        const int start = cur[fb] - cnt[fb];
        const int dstAbs = base[fb] + (i - start);
        if (dstAbs < (r * 64 + fb + 1) * BCAPG)
            srcPart[dstAbs] = sortedL[i];
    }
}

__global__ void normsrc_kernel(const int* __restrict__ deg_out, float* __restrict__ norm_src, int nN) {
    const int n = blockIdx.x * blockDim.x + threadIdx.x;
    if (n < nN) norm_src[n] = rsqrtf((float)max(deg_out[n], 1));
}

// ---------------- gather + per-bucket LDS counting sort + fused layer-2 head fold ----------------
// Changes vs round-3: wave-0 register prefix scan (fewer barriers); paired-node
// gather (joint 16+16 / 8+8 loops -> up to 8 uint4 in flight per lane).
__global__ __launch_bounds__(256)
void gather_sort_kernel(const unsigned short* __restrict__ hs,
                        int* __restrict__ srcPart, const int* __restrict__ gCur,
                        const float* __restrict__ norm_src, const float* __restrict__ bias,
                        const float2* __restrict__ V, float2* __restrict__ uw,
                        int* __restrict__ offs, int* __restrict__ ends,
                        float* __restrict__ norm_dst) {
    __shared__ int cnt[32];
    __shared__ int loc[32];       // inclusive prefix
    __shared__ int cur[32];
    __shared__ int sortedL[BCAPG];

    const int b   = blockIdx.x;
    const int tid = threadIdx.x;
    const int nlo = b * 32;                      // NN == NBUCK*32 exactly
    const int eBase = b * BCAPG;
    const int total = min(gCur[b * GSTRIDE] - eBase, BCAPG);

    if (tid < 32) cnt[tid] = 0;
    __syncthreads();
    for (int i = tid; i < total; i += 256)
        atomicAdd(&cnt[(srcPart[eBase + i] >> 17) & 31], 1);
    __syncthreads();
    if (tid < 64) {                              // wave-0 register prefix scan
        const int l32 = tid & 31;
        const int c = cnt[l32];
        int v = c;
        #pragma unroll
        for (int off = 1; off < 32; off <<= 1) {
            const int t = __shfl_up(v, off, 32);
            if (l32 >= off) v += t;
        }
        if (tid < 32) {
            loc[tid] = v;                        // inclusive prefix
            cur[tid] = v - c;
            const int st = eBase + v - c;
            offs[nlo + tid] = st;
            ends[nlo + tid] = st + c;
            norm_dst[nlo + tid] = rsqrtf((float)max(c, 1));
        }
    }
    __syncthreads();
    for (int i = tid; i < total; i += 256) {
        const int v = srcPart[eBase + i];
        const int r = atomicAdd(&cur[(v >> 17) & 31], 1);
        sortedL[r] = v & 0x1FFFF;
    }
    __syncthreads();
    // coalesced write of sorted src ids (for ac_kernel)
    for (int i = tid; i < total; i += 256)
        srcPart[eBase + i] = sortedL[i];

    // ---- feature gather: paired nodes, 16 lanes/edge, 8 bf16 cols/lane
    const int w  = tid >> 6;
    const int l  = tid & 63;
    const int q  = l >> 4;
    const int c8 = (l & 15) * 8;
    float bb[8];
    *(float4*)&bb[0] = *(const float4*)&bias[c8];
    *(float4*)&bb[4] = *(const float4*)&bias[c8 + 4];
    float2 Vl[8];
    #pragma unroll
    for (int k = 0; k < 8; ++k) Vl[k] = V[c8 + k];

    #pragma unroll 1
    for (int pp = 0; pp < 4; ++pp) {
        const int nhA = w * 8 + 2 * pp;
        const int nhB = nhA + 1;
        const int endA = loc[nhA], cA = cnt[nhA];
        const int endB = loc[nhB], cB = cnt[nhB];
        float accA[8] = {0.f, 0.f, 0.f, 0.f, 0.f, 0.f, 0.f, 0.f};
        float accB[8] = {0.f, 0.f, 0.f, 0.f, 0.f, 0.f, 0.f, 0.f};
        int jA = endA - cA, jB = endB - cB;

        // joint 16+16: 8 uint4 in flight per lane
        for (; jA + 16 <= endA && jB + 16 <= endB; jA += 16, jB += 16) {
            const int a0 = sortedL[jA + q],     a1 = sortedL[jA + 4 + q];
            const int a2 = sortedL[jA + 8 + q], a3 = sortedL[jA + 12 + q];
            const int b0 = sortedL[jB + q],     b1 = sortedL[jB + 4 + q];
            const int b2 = sortedL[jB + 8 + q], b3 = sortedL[jB + 12 + q];
            const float na0 = norm_src[a0], na1 = norm_src[a1];
            const float na2 = norm_src[a2], na3 = norm_src[a3];
            const float nb0 = norm_src[b0], nb1 = norm_src[b1];
            const float nb2 = norm_src[b2], nb3 = norm_src[b3];
            const uint4 va0 = *(const uint4*)&hs[(size_t)a0 * F + c8];
            const uint4 va1 = *(const uint4*)&hs[(size_t)a1 * F + c8];
            const uint4 va2 = *(const uint4*)&hs[(size_t)a2 * F + c8];
            const uint4 va3 = *(const uint4*)&hs[(size_t)a3 * F + c8];
            const uint4 vb0 = *(const uint4*)&hs[(size_t)b0 * F + c8];
            const uint4 vb1 = *(const uint4*)&hs[(size_t)b1 * F + c8];
            const uint4 vb2 = *(const uint4*)&hs[(size_t)b2 * F + c8];
            const uint4 vb3 = *(const uint4*)&hs[(size_t)b3 * F + c8];
            acc_bf8s(va0, na0, accA); acc_bf8s(va1, na1, accA);
            acc_bf8s(va2, na2, accA); acc_bf8s(va3, na3, accA);
            acc_bf8s(vb0, nb0, accB); acc_bf8s(vb1, nb1, accB);
            acc_bf8s(vb2, nb2, accB); acc_bf8s(vb3, nb3, accB);
        }
        // joint 8+8: 4 in flight
        for (; jA + 8 <= endA && jB + 8 <= endB; jA += 8, jB += 8) {
            const int a0 = sortedL[jA + q], a1 = sortedL[jA + 4 + q];
            const int b0 = sortedL[jB + q], b1 = sortedL[jB + 4 + q];
            const float na0 = norm_src[a0], na1 = norm_src[a1];
            const float nb0 = norm_src[b0], nb1 = norm_src[b1];
            const uint4 va0 = *(const uint4*)&hs[(size_t)a0 * F + c8];
            const uint4 va1 = *(const uint4*)&hs[(size_t)a1 * F + c8];
            const uint4 vb0 = *(const uint4*)&hs[(size_t)b0 * F + c8];
            const uint4 vb1 = *(const uint4*)&hs[(size_t)b1 * F + c8];
            acc_bf8s(va0, na0, accA); acc_bf8s(va1, na1, accA);
            acc_bf8s(vb0, nb0, accB); acc_bf8s(vb1, nb1, accB);
        }
        // drain A
        for (; jA + 8 <= endA; jA += 8) {
            const int a0 = sortedL[jA + q], a1 = sortedL[jA + 4 + q];
            const float na0 = norm_src[a0], na1 = norm_src[a1];
            const uint4 va0 = *(const uint4*)&hs[(size_t)a0 * F + c8];
            const uint4 va1 = *(const uint4*)&hs[(size_t)a1 * F + c8];
            acc_bf8s(va0, na0, accA); acc_bf8s(va1, na1, accA);
        }
        for (; jA + 4 <= endA; jA += 4) {
            const int a0 = sortedL[jA + q];
            const float na0 = norm_src[a0];
            const uint4 va0 = *(const uint4*)&hs[(size_t)a0 * F + c8];
            acc_bf8s(va0, na0, accA);
        }
        if (jA + q < endA) {
            const int a0 = sortedL[jA + q];
            const float na0 = norm_src[a0];
            const uint4 va0 = *(const uint4*)&hs[(size_t)a0 * F + c8];
            acc_bf8s(va0, na0, accA);
        }
        // drain B
        for (; jB + 8 <= endB; jB += 8) {
            const int b0 = sortedL[jB + q], b1 = sortedL[jB + 4 + q];
            const float nb0 = norm_src[b0], nb1 = norm_src[b1];
            const uint4 vb0 = *(const uint4*)&hs[(size_t)b0 * F + c8];
            const uint4 vb1 = *(const uint4*)&hs[(size_t)b1 * F + c8];
            acc_bf8s(vb0, nb0, accB); acc_bf8s(vb1, nb1, accB);
        }
        for (; jB + 4 <= endB; jB += 4) {
            const int b0 = sortedL[jB + q];
            const float nb0 = norm_src[b0];
            const uint4 vb0 = *(const uint4*)&hs[(size_t)b0 * F + c8];
            acc_bf8s(vb0, nb0, accB);
        }
        if (jB + q < endB) {
            const int b0 = sortedL[jB + q];
            const float nb0 = norm_src[b0];
            const uint4 vb0 = *(const uint4*)&hs[(size_t)b0 * F + c8];
            acc_bf8s(vb0, nb0, accB);
        }

        // reduce + head-fold A
        #pragma unroll
        for (int k = 0; k < 8; ++k) {
            accA[k] += __shfl_xor(accA[k], 16);
            accA[k] += __shfl_xor(accA[k], 32);
            accB[k] += __shfl_xor(accB[k], 16);
            accB[k] += __shfl_xor(accB[k], 32);
        }
        const float ndA = rsqrtf((float)max(cA, 1));
        const float ndB = rsqrtf((float)max(cB, 1));
        float paA = 0.f, pcA = 0.f, paB = 0.f, pcB = 0.f;
        #pragma unroll
        for (int k = 0; k < 8; ++k) {
            const float okA = fmaxf(accA[k] * ndA + bb[k], 0.f);
            const float okB = fmaxf(accB[k] * ndB + bb[k], 0.f);
            paA += okA * Vl[k].x;
            pcA += okA * Vl[k].y;
            paB += okB * Vl[k].x;
            pcB += okB * Vl[k].y;
        }
        #pragma unroll
        for (int m = 1; m <= 8; m <<= 1) {
            paA += __shfl_xor(paA, m);
            pcA += __shfl_xor(pcA, m);
            paB += __shfl_xor(paB, m);
            pcB += __shfl_xor(pcB, m);
        }
        if (l == 0) {
            const int nA = nlo + nhA;
            const int nB = nlo + nhB;
            uw[nA] = make_float2(norm_src[nA] * paA, norm_src[nA] * pcA);
            uw[nB] = make_float2(norm_src[nB] * paB, norm_src[nB] * pcB);
        }
    }
}

// ---------------- layer-2 scalar aggregation ----------------
__global__ void ac_kernel(const float2* __restrict__ uw, const int* __restrict__ sorted_src,
                          const int* __restrict__ offs, const int* __restrict__ ends,
                          const float* __restrict__ norm_dst,
                          float* __restrict__ A, float* __restrict__ C, int nN) {
    const int n = blockIdx.x * blockDim.x + threadIdx.x;
    if (n >= nN) return;
    const int beg = offs[n];
    const int end = ends[n];
    float su = 0.f, sw = 0.f;
    int j = beg;
    for (; j + 2 <= end; j += 2) {
        const float2 t0 = uw[sorted_src[j]];
        const float2 t1 = uw[sorted_src[j + 1]];
        su += t0.x + t1.x;
        sw += t0.y + t1.y;
    }
    if (j < end) {
        const float2 t = uw[sorted_src[j]];
        su += t.x;
        sw += t.y;
    }
    const float nd = norm_dst[n];
    A[n] = nd * su;
    C[n] = nd * sw;
}

// ---------------- edge scores (4-wide) ----------------
__global__ void score_kernel(const float* __restrict__ A, const float* __restrict__ C,
                             const int4* __restrict__ src4, const int4* __restrict__ dst4,
                             const float* __restrict__ consts, float4* __restrict__ out4,
                             int nE4) {
    const int i = blockIdx.x * blockDim.x + threadIdx.x;
    if (i < nE4) {
        const int4 s = src4[i];
        const int4 d = dst4[i];
        const float cc = consts[0];
        float4 o;
        o.x = 1.f / (1.f + __expf(-(A[s.x] + C[d.x] + cc)));
        o.y = 1.f / (1.f + __expf(-(A[s.y] + C[d.y] + cc)));
        o.z = 1.f / (1.f + __expf(-(A[s.z] + C[d.z] + cc)));
        o.w = 1.f / (1.f + __expf(-(A[s.w] + C[d.w] + cc)));
        out4[i] = o;
    }
}

extern "C" void kernel_launch(void* const* d_in, const int* in_sizes, int n_in,
                              void* d_out, int out_size, void* d_ws, size_t ws_size,
                              hipStream_t stream) {
    const float* x  = (const float*)d_in[0];
    const float* W1 = (const float*)d_in[1];
    const float* b1 = (const float*)d_in[2];
    const float* W2 = (const float*)d_in[3];
    const float* b2 = (const float*)d_in[4];
    const float* Wp = (const float*)d_in[5];
    const float* bp = (const float*)d_in[6];
    const int*   src = (const int*)d_in[7];
    const int*   dst = (const int*)d_in[8];
    float* out = (float*)d_out;

    float* ws        = (float*)d_ws;
    float* norm_src  = ws;                        // NPAD
    float* bufA      = ws + NPAD;                 // NPAD: deg_out(int), later A[]
    float* bufC      = ws + 2 * NPAD;             // NPAD: C[]
    float* norm_dst  = ws + 3 * NPAD;             // NPAD
    int*   offs      = (int*)(ws + 4 * NPAD);     // NPAD
    int*   ends      = offs + NPAD;               // NPAD
    int*   gCur      = ends + NPAD;               // NBUCK*GSTRIDE = 50000, pad 50176
    int*   gRegCur   = gCur + 50176;              // NREG*GSTRIDE = 784, pad 1024
    float* consts    = (float*)(gRegCur + 1024);  // 16
    float2* V        = (float2*)(consts + 16);    // 128 float2
    float2* uw       = V + 128;                   // NN float2
    int*   srcPart   = (int*)(uw + NN);           // NBUCK*BCAPG ints (9.6 MB)
    unsigned short* hs_bf = (unsigned short*)(srcPart + (size_t)NBUCK * BCAPG);  // NN*F bf16
    int*   gRegion   = (int*)(hs_bf + (size_t)NN * F);  // NREG*RCAP ints (7.2 MB)

    // init counters + folded head weights (one setup kernel)
    hipMemsetAsync(bufA, 0, NPAD * sizeof(int), stream);        // deg_out
    setup_kernel<<<14, 256, 0, stream>>>(gCur, gRegCur, W2, Wp, b2, bp, consts, V);

    // layer-1 MFMA GEMM overlapped with degree count + pass-1 coarse binning
    gemm1_fill_kernel<<<768, 256, 0, stream>>>(x, W1, hs_bf, src, dst,
                                               (int*)bufA, gRegCur, gRegion);

    // pass 2: coarse regions -> fine 32-node buckets, coalesced both ways
    pass2_kernel<<<NREG * P2SPLIT, 256, 0, stream>>>(gRegion, gRegCur, gCur, srcPart);

    normsrc_kernel<<<(NN + 255) / 256, 256, 0, stream>>>((const int*)bufA, norm_src, NN);

    // per-bucket LDS sort + paired-node feature gather + folded layer-2 head
    gather_sort_kernel<<<NBUCK, 256, 0, stream>>>(hs_bf, srcPart, gCur, norm_src, b1,
                                                  V, uw, offs, ends, norm_dst);

    // layer-2 aggregation collapsed to scalar sums
    ac_kernel<<<(NN + 255) / 256, 256, 0, stream>>>(uw, srcPart, offs, ends, norm_dst,
                                                    bufA, bufC, NN);

    // edge scores (NE divisible by 4)
    score_kernel<<<(NE / 4 + 255) / 256, 256, 0, stream>>>(bufA, bufC, (const int4*)src,
                                                           (const int4*)dst, consts,
                                                           (float4*)out, NE / 4);
}

// Round 9
// 303.253 us; speedup vs baseline: 1.1274x; 1.0226x over previous
//
#include <hip/hip_runtime.h>
#include <cstdint>
#include <cstddef>

#define NN 100000
#define NE 1600000
#define F  128
#define NPAD 100352          // 98 * 1024
#define NBUCK 3125           // NN / 32 fine buckets of 32 nodes (gather granularity)
#define BCAPG 768            // fine bucket capacity (mean 512, +11 sd)
#define CHUNK 4167           // ceil(NE / 384) fill chunks
#define GSTRIDE 16           // cursor padding: one counter per 64B line
#define NREG 49              // coarse regions by d>>11 (2048 nodes each)
#define RCAP 36864           // region capacity (mean ~32650, +23 sd)
#define P2SPLIT 16           // pass-2 blocks per region
#define P2MAX 2304           // ceil(RCAP / P2SPLIT)

typedef __attribute__((ext_vector_type(8))) short bf16x8;
typedef __attribute__((ext_vector_type(4))) float f32x4;

// bf16 helpers (RNE)
__device__ __forceinline__ unsigned short f2bf(float f) {
    unsigned u = __float_as_uint(f);
    unsigned r = (u + 0x7fffu + ((u >> 16) & 1u)) >> 16;
    return (unsigned short)r;
}
__device__ __forceinline__ void acc_bf8s(const uint4 v, const float ns, float* acc) {
    acc[0] += __uint_as_float(v.x << 16) * ns;
    acc[1] += __uint_as_float(v.x & 0xffff0000u) * ns;
    acc[2] += __uint_as_float(v.y << 16) * ns;
    acc[3] += __uint_as_float(v.y & 0xffff0000u) * ns;
    acc[4] += __uint_as_float(v.z << 16) * ns;
    acc[5] += __uint_as_float(v.z & 0xffff0000u) * ns;
    acc[6] += __uint_as_float(v.w << 16) * ns;
    acc[7] += __uint_as_float(v.w & 0xffff0000u) * ns;
}

// ---------------- setup: cursors + head constant + V = W2 @ Wp ----------------
__global__ void setup_kernel(int* __restrict__ gCur, int* __restrict__ gRegCur,
                             const float* __restrict__ W2, const float* __restrict__ Wp,
                             const float* __restrict__ b2, const float* __restrict__ bp,
                             float* __restrict__ consts, float2* __restrict__ V) {
    const int g = blockIdx.x;
    const int tid = threadIdx.x;
    if (g < 13) {                         // 13*256 = 3328 >= NBUCK
        const int b = g * 256 + tid;
        if (b < NBUCK) gCur[b * GSTRIDE] = b * BCAPG;
        return;
    }
    // block 13: head fold weights + constant + region cursors
    if (tid < 128) {                      // V[i] = (W2[i]·Wp_a, W2[i]·Wp_c)
        float sa = 0.f, sc = 0.f;
        #pragma unroll 8
        for (int j = 0; j < F; ++j) {
            const float w = W2[tid * F + j];
            sa += w * Wp[j];
            sc += w * Wp[F + j];
        }
        V[tid] = make_float2(sa, sc);
    } else if (tid < 192) {               // wave 2: cc = b2.Wp_a + b2.Wp_c + bp
        const int l = tid - 128;
        const float2 bb = *(const float2*)&b2[2 * l];
        const float2 wa = *(const float2*)&Wp[2 * l];
        const float2 wc = *(const float2*)&Wp[F + 2 * l];
        float s = bb.x * (wa.x + wc.x) + bb.y * (wa.y + wc.y);
        #pragma unroll
        for (int m = 32; m > 0; m >>= 1) s += __shfl_xor(s, m);
        if (l == 0) consts[0] = s + bp[0];
    } else if (tid < 192 + NREG) {        // wave 3: region cursors
        const int r = tid - 192;
        gRegCur[r * GSTRIDE] = r * RCAP;
    }
}

// ---------------- fused gemm1 (MFMA) + pass-1 coarse binning [round-3 proven] ----------------
__global__ __launch_bounds__(256, 3)
void gemm1_fill_kernel(const float* __restrict__ in, const float* __restrict__ W,
                       unsigned short* __restrict__ out_bf,
                       const int* __restrict__ src, const int* __restrict__ dst,
                       int* __restrict__ deg_out, int* __restrict__ gRegCur,
                       int* __restrict__ gRegion) {
    __shared__ __align__(16) char smem[21504];

    const int g = blockIdx.x;
    const int tid = threadIdx.x;

    if (g & 1) {                                    // ---- fill role (384 blocks)
        int* sortedL = (int*)smem;                          // CHUNK ints   (16668 B)
        unsigned char* regOf = (unsigned char*)(sortedL + CHUNK);  // CHUNK u8 (4167 B)
        int* cnt  = (int*)(smem + 20840);                   // NREG ints
        int* cur  = cnt + NREG;                             // NREG ints
        int* base = cur + NREG;                             // NREG ints

        const int e0 = (g >> 1) * CHUNK;
        const int nCh = min(CHUNK, NE - e0);
        if (tid < NREG) cnt[tid] = 0;
        __syncthreads();
        for (int i = tid; i < nCh; i += 256) {
            const int s = src[e0 + i];
            const int d = dst[e0 + i];
            atomicAdd(&deg_out[s], 1);
            atomicAdd(&cnt[d >> 11], 1);
        }
        __syncthreads();
        if (tid < NREG && cnt[tid] > 0)
            base[tid] = atomicAdd(&gRegCur[tid * GSTRIDE], cnt[tid]);
        if (tid == 0) {
            int run = 0;
            for (int r = 0; r < NREG; ++r) { cur[r] = run; run += cnt[r]; }
        }
        __syncthreads();
        // place into LDS grouped by region (src/dst re-read: L1/L2-hot)
        for (int i = tid; i < nCh; i += 256) {
            const int s = src[e0 + i];
            const int d = dst[e0 + i];
            const int r = d >> 11;
            const int p = atomicAdd(&cur[r], 1);
            sortedL[p] = s | ((d & 0x7FF) << 17);
            regOf[p] = (unsigned char)r;
        }
        __syncthreads();
        // coalesced copy-out: contiguous runs per region
        for (int i = tid; i < nCh; i += 256) {
            const int r = regOf[i];
            const int start = cur[r] - cnt[r];          // cur advanced to end
            const int dstAbs = base[r] + (i - start);
            if (dstAbs < (r + 1) * RCAP)
                gRegion[dstAbs] = sortedL[i];
        }
        return;
    }

    // ---- gemm role (384 blocks), tile = 32 rows x 128 cols
    char* A_s = smem;                   // 8 KB fragment-ordered A tile (bf16)

    const int gid  = g >> 1;
    const int w    = tid >> 6;          // wave 0..3 -> cols 32w..32w+31
    const int lane = tid & 63;
    const int ml   = lane & 15;
    const int quad = lane >> 4;

    // preload B frags once: Bf[kb][nb], j: bf16(W[(kb*32+quad*8+j)*F + 32w+nb*16+ml])
    bf16x8 Bf[4][2];
    #pragma unroll
    for (int kb = 0; kb < 4; ++kb) {
        #pragma unroll
        for (int nb = 0; nb < 2; ++nb) {
            const int n = 32 * w + nb * 16 + ml;
            const int k0 = kb * 32 + quad * 8;
            #pragma unroll
            for (int j = 0; j < 8; ++j)
                Bf[kb][nb][j] = (short)f2bf(W[(k0 + j) * F + n]);
        }
    }

    const int nTiles = NN / 32;                     // 3125
    for (int tile = gid; tile < nTiles; tile += 384) {
        const int row0 = tile * 32;
        __syncthreads();
        // stage A tile in fragment order: 512 chunks of 8 floats -> bf16
        #pragma unroll
        for (int c = 0; c < 2; ++c) {
            const int i2 = tid + 256 * c;           // 0..511
            const int m  = i2 >> 4;                 // row 0..31
            const int o  = i2 & 15;                 // k-octet
            const float* xr = &in[(size_t)(row0 + m) * F + o * 8];
            const float4 v0 = *(const float4*)xr;
            const float4 v1 = *(const float4*)(xr + 4);
            short h8[8];
            h8[0] = (short)f2bf(v0.x); h8[1] = (short)f2bf(v0.y);
            h8[2] = (short)f2bf(v0.z); h8[3] = (short)f2bf(v0.w);
            h8[4] = (short)f2bf(v1.x); h8[5] = (short)f2bf(v1.y);
            h8[6] = (short)f2bf(v1.z); h8[7] = (short)f2bf(v1.w);
            const int kb2 = o >> 2, q2 = o & 3, ml2 = m & 15, mh2 = m >> 4;
            const int fo = (((mh2 * 4 + kb2) * 64) + q2 * 16 + ml2) * 16;
            *(bf16x8*)(A_s + fo) = *(bf16x8*)h8;
        }
        __syncthreads();

        f32x4 acc00 = {0,0,0,0}, acc01 = {0,0,0,0}, acc10 = {0,0,0,0}, acc11 = {0,0,0,0};
        #pragma unroll
        for (int kb = 0; kb < 4; ++kb) {
            const bf16x8 ah0 = *(const bf16x8*)(A_s + (kb * 64 + lane) * 16);
            const bf16x8 ah1 = *(const bf16x8*)(A_s + ((4 + kb) * 64 + lane) * 16);
            acc00 = __builtin_amdgcn_mfma_f32_16x16x32_bf16(ah0, Bf[kb][0], acc00, 0, 0, 0);
            acc01 = __builtin_amdgcn_mfma_f32_16x16x32_bf16(ah0, Bf[kb][1], acc01, 0, 0, 0);
            acc10 = __builtin_amdgcn_mfma_f32_16x16x32_bf16(ah1, Bf[kb][0], acc10, 0, 0, 0);
            acc11 = __builtin_amdgcn_mfma_f32_16x16x32_bf16(ah1, Bf[kb][1], acc11, 0, 0, 0);
        }

        // epilogue: C/D layout col=lane&15, row=quad*4+reg
        #pragma unroll
        for (int mh = 0; mh < 2; ++mh) {
            #pragma unroll
            for (int nb = 0; nb < 2; ++nb) {
                const f32x4 a = (mh == 0) ? (nb == 0 ? acc00 : acc01)
                                          : (nb == 0 ? acc10 : acc11);
                const int row = row0 + mh * 16 + quad * 4;
                const int col = 32 * w + nb * 16 + ml;
                #pragma unroll
                for (int r = 0; r < 4; ++r)
                    out_bf[(size_t)(row + r) * F + col] = f2bf(a[r]);
            }
        }
    }
}

// ---------------- pass 2: coarse region -> fine 32-node buckets (coalesced) ----------------
__global__ __launch_bounds__(256)
void pass2_kernel(const int* __restrict__ gRegion, const int* __restrict__ gRegCur,
                  int* __restrict__ gCur, int* __restrict__ srcPart) {
    __shared__ int sortedL[P2MAX];
    __shared__ unsigned char fbOf[P2MAX];
    __shared__ int cnt[64], cur[64], base[64];

    const int r   = blockIdx.x / P2SPLIT;
    const int j   = blockIdx.x % P2SPLIT;
    const int tid = threadIdx.x;

    const int total = min(gRegCur[r * GSTRIDE] - r * RCAP, RCAP);
    const int per = (total + P2SPLIT - 1) / P2SPLIT;
    const int i0 = j * per;
    const int i1 = min(total, i0 + per);
    const int n = i1 - i0;                       // may be <= 0 for tail blocks

    if (tid < 64) cnt[tid] = 0;
    __syncthreads();

    int v[9];                                    // ceil(P2MAX/256) = 9
    #pragma unroll
    for (int k = 0; k < 9; ++k) {
        const int i = tid + k * 256;
        if (i < n) {
            const int vv = gRegion[r * RCAP + i0 + i];
            v[k] = vv;
            atomicAdd(&cnt[vv >> 22], 1);        // fb = (d&0x7FF)>>5
        }
    }
    __syncthreads();
    if (tid < 64 && cnt[tid] > 0)
        base[tid] = atomicAdd(&gCur[(r * 64 + tid) * GSTRIDE], cnt[tid]);
    if (tid == 0) {
        int run = 0;
        for (int f = 0; f < 64; ++f) { cur[f] = run; run += cnt[f]; }
    }
    __syncthreads();
    #pragma unroll
    for (int k = 0; k < 9; ++k) {
        const int i = tid + k * 256;
        if (i < n) {
            const int fb = v[k] >> 22;
            const int p = atomicAdd(&cur[fb], 1);
            sortedL[p] = v[k] & 0x3FFFFF;        // s | ((d&31)<<17)
            fbOf[p] = (unsigned char)fb;
        }
    }
    __syncthreads();
    for (int i = tid; i < n; i += 256) {
        const int fb = fbOf[i];
        const int start = cur[fb] - cnt[fb];
        const int dstAbs = base[fb] + (i - start);
        if (dstAbs < (r * 64 + fb + 1) * BCAPG)
            srcPart[dstAbs] = sortedL[i];
    }
}

__global__ void normsrc_kernel(const int* __restrict__ deg_out, float* __restrict__ norm_src, int nN) {
    const int n = blockIdx.x * blockDim.x + threadIdx.x;
    if (n < nN) norm_src[n] = rsqrtf((float)max(deg_out[n], 1));
}

// ---------------- gather + per-bucket LDS counting sort + fused layer-2 head fold ----------------
// Round-3 proven single-node gather loop (VGPR ~48, occ ~44%) + wave-0 register scan.
__global__ __launch_bounds__(256)
void gather_sort_kernel(const unsigned short* __restrict__ hs,
                        int* __restrict__ srcPart, const int* __restrict__ gCur,
                        const float* __restrict__ norm_src, const float* __restrict__ bias,
                        const float2* __restrict__ V, float2* __restrict__ uw,
                        int* __restrict__ offs, int* __restrict__ ends,
                        float* __restrict__ norm_dst) {
    __shared__ int cnt[32];
    __shared__ int loc[32];       // inclusive prefix
    __shared__ int cur[32];
    __shared__ int sortedL[BCAPG];

    const int b   = blockIdx.x;
    const int tid = threadIdx.x;
    const int nlo = b * 32;                      // NN == NBUCK*32 exactly
    const int eBase = b * BCAPG;
    const int total = min(gCur[b * GSTRIDE] - eBase, BCAPG);

    if (tid < 32) cnt[tid] = 0;
    __syncthreads();
    for (int i = tid; i < total; i += 256)
        atomicAdd(&cnt[(srcPart[eBase + i] >> 17) & 31], 1);
    __syncthreads();
    if (tid < 64) {                              // wave-0 register prefix scan
        const int l32 = tid & 31;
        const int c = cnt[l32];
        int v = c;
        #pragma unroll
        for (int off = 1; off < 32; off <<= 1) {
            const int t = __shfl_up(v, off, 32);
            if (l32 >= off) v += t;
        }
        if (tid < 32) {
            loc[tid] = v;                        // inclusive prefix
            cur[tid] = v - c;
            const int st = eBase + v - c;
            offs[nlo + tid] = st;
            ends[nlo + tid] = st + c;
            norm_dst[nlo + tid] = rsqrtf((float)max(c, 1));
        }
    }
    __syncthreads();
    for (int i = tid; i < total; i += 256) {
        const int v = srcPart[eBase + i];
        const int r = atomicAdd(&cur[(v >> 17) & 31], 1);
        sortedL[r] = v & 0x1FFFF;
    }
    __syncthreads();
    // coalesced write of sorted src ids (for ac_kernel)
    for (int i = tid; i < total; i += 256)
        srcPart[eBase + i] = sortedL[i];

    // ---- feature gather (per wave: 8 nodes; 16 lanes per edge, 8 bf16 cols/lane)
    const int w  = tid >> 6;
    const int l  = tid & 63;
    const int q  = l >> 4;
    const int c8 = (l & 15) * 8;
    float bb[8];
    *(float4*)&bb[0] = *(const float4*)&bias[c8];
    *(float4*)&bb[4] = *(const float4*)&bias[c8 + 4];
    float2 Vl[8];
    #pragma unroll
    for (int k = 0; k < 8; ++k) Vl[k] = V[c8 + k];

    const int nhEnd = (w + 1) * 8;
    for (int nh = w * 8; nh < nhEnd; ++nh) {
        const int end = loc[nh];
        const int beg = end - cnt[nh];
        float acc[8] = {0.f, 0.f, 0.f, 0.f, 0.f, 0.f, 0.f, 0.f};
        int j = beg;
        for (; j + 16 <= end; j += 16) {      // 16 edges in flight per wave
            const int s0 = sortedL[j + q];
            const int s1 = sortedL[j + 4 + q];
            const int s2 = sortedL[j + 8 + q];
            const int s3 = sortedL[j + 12 + q];
            const float ns0 = norm_src[s0];
            const float ns1 = norm_src[s1];
            const float ns2 = norm_src[s2];
            const float ns3 = norm_src[s3];
            const uint4 v0 = *(const uint4*)&hs[(size_t)s0 * F + c8];
            const uint4 v1 = *(const uint4*)&hs[(size_t)s1 * F + c8];
            const uint4 v2 = *(const uint4*)&hs[(size_t)s2 * F + c8];
            const uint4 v3 = *(const uint4*)&hs[(size_t)s3 * F + c8];
            acc_bf8s(v0, ns0, acc);
            acc_bf8s(v1, ns1, acc);
            acc_bf8s(v2, ns2, acc);
            acc_bf8s(v3, ns3, acc);
        }
        for (; j + 8 <= end; j += 8) {
            const int s0 = sortedL[j + q];
            const int s1 = sortedL[j + 4 + q];
            const float ns0 = norm_src[s0];
            const float ns1 = norm_src[s1];
            const uint4 v0 = *(const uint4*)&hs[(size_t)s0 * F + c8];
            const uint4 v1 = *(const uint4*)&hs[(size_t)s1 * F + c8];
            acc_bf8s(v0, ns0, acc);
            acc_bf8s(v1, ns1, acc);
        }
        for (; j + 4 <= end; j += 4) {
            const int s = sortedL[j + q];
            const float ns = norm_src[s];
            const uint4 v = *(const uint4*)&hs[(size_t)s * F + c8];
            acc_bf8s(v, ns, acc);
        }
        if (j + q < end) {
            const int s = sortedL[j + q];
            const float ns = norm_src[s];
            const uint4 v = *(const uint4*)&hs[(size_t)s * F + c8];
            acc_bf8s(v, ns, acc);
        }
        #pragma unroll
        for (int k = 0; k < 8; ++k) {
            acc[k] += __shfl_xor(acc[k], 16);
            acc[k] += __shfl_xor(acc[k], 32);
        }

        const int n = nlo + nh;
        const float nd = rsqrtf((float)max(cnt[nh], 1));
        float pa = 0.f, pc = 0.f;
        #pragma unroll
        for (int k = 0; k < 8; ++k) {
            const float ok = fmaxf(acc[k] * nd + bb[k], 0.f);
            pa += ok * Vl[k].x;
            pc += ok * Vl[k].y;
        }
        #pragma unroll
        for (int m = 1; m <= 8; m <<= 1) {
            pa += __shfl_xor(pa, m);
            pc += __shfl_xor(pc, m);
        }
        if (l == 0) {
            const float ns = norm_src[n];
            uw[n] = make_float2(ns * pa, ns * pc);
        }
    }
}

// ---------------- layer-2 aggregation: bucket-parallel (8 threads/node) ----------------
// Old version: 391 blocks (1.5/CU), thread-per-node, ~16 serial random loads each.
// New: block per bucket (3125 blocks, ~12/CU), 8 threads/node stride the sorted
// edge slice, 3-step shuffle reduce — serial load depth 16 -> ~2.
__global__ __launch_bounds__(256, 8)
void ac_kernel(const float2* __restrict__ uw, const int* __restrict__ sorted_src,
               const int* __restrict__ offs, const int* __restrict__ ends,
               const float* __restrict__ norm_dst,
               float* __restrict__ A, float* __restrict__ C) {
    const int tid = threadIdx.x;
    const int n   = blockIdx.x * 32 + (tid >> 3);   // NN == NBUCK*32 exactly
    const int sub = tid & 7;
    const int beg = offs[n];
    const int end = ends[n];
    float sx = 0.f, sy = 0.f;
    for (int j = beg + sub; j < end; j += 8) {
        const float2 t = uw[sorted_src[j]];
        sx += t.x;
        sy += t.y;
    }
    sx += __shfl_xor(sx, 1); sy += __shfl_xor(sy, 1);
    sx += __shfl_xor(sx, 2); sy += __shfl_xor(sy, 2);
    sx += __shfl_xor(sx, 4); sy += __shfl_xor(sy, 4);
    if (sub == 0) {
        const float nd = norm_dst[n];
        A[n] = nd * sx;
        C[n] = nd * sy;
    }
}

// ---------------- edge scores (4-wide) ----------------
__global__ void score_kernel(const float* __restrict__ A, const float* __restrict__ C,
                             const int4* __restrict__ src4, const int4* __restrict__ dst4,
                             const float* __restrict__ consts, float4* __restrict__ out4,
                             int nE4) {
    const int i = blockIdx.x * blockDim.x + threadIdx.x;
    if (i < nE4) {
        const int4 s = src4[i];
        const int4 d = dst4[i];
        const float cc = consts[0];
        float4 o;
        o.x = 1.f / (1.f + __expf(-(A[s.x] + C[d.x] + cc)));
        o.y = 1.f / (1.f + __expf(-(A[s.y] + C[d.y] + cc)));
        o.z = 1.f / (1.f + __expf(-(A[s.z] + C[d.z] + cc)));
        o.w = 1.f / (1.f + __expf(-(A[s.w] + C[d.w] + cc)));
        out4[i] = o;
    }
}

extern "C" void kernel_launch(void* const* d_in, const int* in_sizes, int n_in,
                              void* d_out, int out_size, void* d_ws, size_t ws_size,
                              hipStream_t stream) {
    const float* x  = (const float*)d_in[0];
    const float* W1 = (const float*)d_in[1];
    const float* b1 = (const float*)d_in[2];
    const float* W2 = (const float*)d_in[3];
    const float* b2 = (const float*)d_in[4];
    const float* Wp = (const float*)d_in[5];
    const float* bp = (const float*)d_in[6];
    const int*   src = (const int*)d_in[7];
    const int*   dst = (const int*)d_in[8];
    float* out = (float*)d_out;

    float* ws        = (float*)d_ws;
    float* norm_src  = ws;                        // NPAD
    float* bufA      = ws + NPAD;                 // NPAD: deg_out(int), later A[]
    float* bufC      = ws + 2 * NPAD;             // NPAD: C[]
    float* norm_dst  = ws + 3 * NPAD;             // NPAD
    int*   offs      = (int*)(ws + 4 * NPAD);     // NPAD
    int*   ends      = offs + NPAD;               // NPAD
    int*   gCur      = ends + NPAD;               // NBUCK*GSTRIDE = 50000, pad 50176
    int*   gRegCur   = gCur + 50176;              // NREG*GSTRIDE = 784, pad 1024
    float* consts    = (float*)(gRegCur + 1024);  // 16
    float2* V        = (float2*)(consts + 16);    // 128 float2
    float2* uw       = V + 128;                   // NN float2
    int*   srcPart   = (int*)(uw + NN);           // NBUCK*BCAPG ints (9.6 MB)
    unsigned short* hs_bf = (unsigned short*)(srcPart + (size_t)NBUCK * BCAPG);  // NN*F bf16
    int*   gRegion   = (int*)(hs_bf + (size_t)NN * F);  // NREG*RCAP ints (7.2 MB)

    // init counters + folded head weights (one setup kernel)
    hipMemsetAsync(bufA, 0, NPAD * sizeof(int), stream);        // deg_out
    setup_kernel<<<14, 256, 0, stream>>>(gCur, gRegCur, W2, Wp, b2, bp, consts, V);

    // layer-1 MFMA GEMM overlapped with degree count + pass-1 coarse binning
    gemm1_fill_kernel<<<768, 256, 0, stream>>>(x, W1, hs_bf, src, dst,
                                               (int*)bufA, gRegCur, gRegion);

    // pass 2: coarse regions -> fine 32-node buckets, coalesced both ways
    pass2_kernel<<<NREG * P2SPLIT, 256, 0, stream>>>(gRegion, gRegCur, gCur, srcPart);

    normsrc_kernel<<<(NN + 255) / 256, 256, 0, stream>>>((const int*)bufA, norm_src, NN);

    // per-bucket LDS sort + feature gather + folded layer-2 head
    gather_sort_kernel<<<NBUCK, 256, 0, stream>>>(hs_bf, srcPart, gCur, norm_src, b1,
                                                  V, uw, offs, ends, norm_dst);

    // layer-2 aggregation: bucket-parallel, 8 threads per node
    ac_kernel<<<NBUCK, 256, 0, stream>>>(uw, srcPart, offs, ends, norm_dst,
                                         bufA, bufC);

    // edge scores (NE divisible by 4)
    score_kernel<<<(NE / 4 + 255) / 256, 256, 0, stream>>>(bufA, bufC, (const int4*)src,
                                                           (const int4*)dst, consts,
                                                           (float4*)out, NE / 4);
}

// Round 10
// 285.058 us; speedup vs baseline: 1.1994x; 1.0638x over previous
//
#include <hip/hip_runtime.h>
#include <cstdint>
#include <cstddef>

#define NN 100000
#define NE 1600000
#define F  128
#define NPAD 100352          // 98 * 1024
#define NBUCK 3125           // NN / 32 fine buckets of 32 nodes (gather granularity)
#define BCAPG 768            // fine bucket capacity (mean 512, +11 sd)
#define CHUNK 4167           // ceil(NE / 384) fill chunks
#define GSTRIDE 16           // cursor padding: one counter per 64B line
#define NREG 49              // coarse regions (2048 nodes each)
#define RCAP 36864           // region capacity (mean ~32650, +23 sd)
#define P2SPLIT 16           // pass-2 sort blocks per region
#define P2J 17               // + 1 deg-histogram block per region
#define P2MAX 2304           // ceil(RCAP / P2SPLIT)

typedef __attribute__((ext_vector_type(8))) short bf16x8;
typedef __attribute__((ext_vector_type(4))) float f32x4;

// bf16 helpers (RNE)
__device__ __forceinline__ unsigned short f2bf(float f) {
    unsigned u = __float_as_uint(f);
    unsigned r = (u + 0x7fffu + ((u >> 16) & 1u)) >> 16;
    return (unsigned short)r;
}
__device__ __forceinline__ void acc_bf8s(const uint4 v, const float ns, float* acc) {
    acc[0] += __uint_as_float(v.x << 16) * ns;
    acc[1] += __uint_as_float(v.x & 0xffff0000u) * ns;
    acc[2] += __uint_as_float(v.y << 16) * ns;
    acc[3] += __uint_as_float(v.y & 0xffff0000u) * ns;
    acc[4] += __uint_as_float(v.z << 16) * ns;
    acc[5] += __uint_as_float(v.z & 0xffff0000u) * ns;
    acc[6] += __uint_as_float(v.w << 16) * ns;
    acc[7] += __uint_as_float(v.w & 0xffff0000u) * ns;
}

// ---------------- setup: cursors + head constant + V = W2 @ Wp ----------------
__global__ void setup_kernel(int* __restrict__ gCur, int* __restrict__ gRegCur,
                             int* __restrict__ gRegCurS,
                             const float* __restrict__ W2, const float* __restrict__ Wp,
                             const float* __restrict__ b2, const float* __restrict__ bp,
                             float* __restrict__ consts, float2* __restrict__ V) {
    const int g = blockIdx.x;
    const int tid = threadIdx.x;
    if (g < 13) {                         // 13*256 = 3328 >= NBUCK
        const int b = g * 256 + tid;
        if (b < NBUCK) gCur[b * GSTRIDE] = b * BCAPG;
        return;
    }
    if (g == 14) {                        // region cursors (both streams)
        if (tid < NREG) gRegCur[tid * GSTRIDE] = tid * RCAP;
        else if (tid >= 64 && tid < 64 + NREG) {
            const int r = tid - 64;
            gRegCurS[r * GSTRIDE] = r * RCAP;
        }
        return;
    }
    // block 13: head fold weights + constant
    if (tid < 128) {                      // V[i] = (W2[i]·Wp_a, W2[i]·Wp_c)
        float sa = 0.f, sc = 0.f;
        #pragma unroll 8
        for (int j = 0; j < F; ++j) {
            const float w = W2[tid * F + j];
            sa += w * Wp[j];
            sc += w * Wp[F + j];
        }
        V[tid] = make_float2(sa, sc);
    } else if (tid < 192) {               // wave 2: cc = b2.Wp_a + b2.Wp_c + bp
        const int l = tid - 128;
        const float2 bb = *(const float2*)&b2[2 * l];
        const float2 wa = *(const float2*)&Wp[2 * l];
        const float2 wc = *(const float2*)&Wp[F + 2 * l];
        float s = bb.x * (wa.x + wc.x) + bb.y * (wa.y + wc.y);
        #pragma unroll
        for (int m = 32; m > 0; m >>= 1) s += __shfl_xor(s, m);
        if (l == 0) consts[0] = s + bp[0];
    }
}

// ---------------- fused gemm1 (MFMA) + dual-stream coarse binning ----------------
// blockIdx%2==1 -> fill role: TWO LDS counting sorts of a 4167-edge chunk:
//   round 1 by dst>>11 -> gRegion (packed s|(d&0x7FF)<<17), coalesced runs;
//   round 2 by src>>11 -> gRegionS (u16 s&0x7FF), coalesced runs.
//   ZERO per-edge global atomics — deg_out is derived in pass2 by LDS histogram
//   (round-5 counter evidence: 1.6M random atomicAdds = ~51 MB RMW line traffic).
// blockIdx%2==0 -> gemm role: hs_bf[n][:] = bf16(x[n][:] @ W1), 32x128 MFMA tiles.
__global__ __launch_bounds__(256, 3)
void gemm1_fill_kernel(const float* __restrict__ in, const float* __restrict__ W,
                       unsigned short* __restrict__ out_bf,
                       const int* __restrict__ src, const int* __restrict__ dst,
                       int* __restrict__ gRegCur, int* __restrict__ gRegCurS,
                       int* __restrict__ gRegion, unsigned short* __restrict__ gRegionS) {
    __shared__ __align__(16) char smem[21504];

    const int g = blockIdx.x;
    const int tid = threadIdx.x;

    if (g & 1) {                                    // ---- fill role (384 blocks)
        int* sortedL = (int*)smem;                          // CHUNK ints   (16668 B)
        unsigned char* regOf = (unsigned char*)(sortedL + CHUNK);  // CHUNK u8 (4167 B)
        int* cnt  = (int*)(smem + 20840);                   // NREG ints
        int* cur  = cnt + NREG;                             // NREG ints
        int* base = cur + NREG;                             // NREG ints

        const int e0 = (g >> 1) * CHUNK;
        const int nCh = min(CHUNK, NE - e0);

        // ---- round 1: key = dst >> 11
        if (tid < NREG) cnt[tid] = 0;
        __syncthreads();
        for (int i = tid; i < nCh; i += 256)
            atomicAdd(&cnt[dst[e0 + i] >> 11], 1);
        __syncthreads();
        if (tid < NREG && cnt[tid] > 0)
            base[tid] = atomicAdd(&gRegCur[tid * GSTRIDE], cnt[tid]);
        if (tid == 0) {
            int run = 0;
            for (int r = 0; r < NREG; ++r) { cur[r] = run; run += cnt[r]; }
        }
        __syncthreads();
        for (int i = tid; i < nCh; i += 256) {
            const int s = src[e0 + i];
            const int d = dst[e0 + i];
            const int r = d >> 11;
            const int p = atomicAdd(&cur[r], 1);
            sortedL[p] = s | ((d & 0x7FF) << 17);
            regOf[p] = (unsigned char)r;
        }
        __syncthreads();
        for (int i = tid; i < nCh; i += 256) {
            const int r = regOf[i];
            const int dstAbs = base[r] + (i - (cur[r] - cnt[r]));
            if (dstAbs < (r + 1) * RCAP)
                gRegion[dstAbs] = sortedL[i];
        }
        __syncthreads();

        // ---- round 2: key = src >> 11 (deg stream, u16 payload)
        if (tid < NREG) cnt[tid] = 0;
        __syncthreads();
        for (int i = tid; i < nCh; i += 256)
            atomicAdd(&cnt[src[e0 + i] >> 11], 1);
        __syncthreads();
        if (tid < NREG && cnt[tid] > 0)
            base[tid] = atomicAdd(&gRegCurS[tid * GSTRIDE], cnt[tid]);
        if (tid == 0) {
            int run = 0;
            for (int r = 0; r < NREG; ++r) { cur[r] = run; run += cnt[r]; }
        }
        __syncthreads();
        for (int i = tid; i < nCh; i += 256) {
            const int s = src[e0 + i];
            const int r = s >> 11;
            const int p = atomicAdd(&cur[r], 1);
            sortedL[p] = s;
            regOf[p] = (unsigned char)r;
        }
        __syncthreads();
        for (int i = tid; i < nCh; i += 256) {
            const int r = regOf[i];
            const int dstAbs = base[r] + (i - (cur[r] - cnt[r]));
            if (dstAbs < (r + 1) * RCAP)
                gRegionS[dstAbs] = (unsigned short)(sortedL[i] & 0x7FF);
        }
        return;
    }

    // ---- gemm role (384 blocks), tile = 32 rows x 128 cols
    char* A_s = smem;                   // 8 KB fragment-ordered A tile (bf16)

    const int gid  = g >> 1;
    const int w    = tid >> 6;          // wave 0..3 -> cols 32w..32w+31
    const int lane = tid & 63;
    const int ml   = lane & 15;
    const int quad = lane >> 4;

    // preload B frags once: Bf[kb][nb], j: bf16(W[(kb*32+quad*8+j)*F + 32w+nb*16+ml])
    bf16x8 Bf[4][2];
    #pragma unroll
    for (int kb = 0; kb < 4; ++kb) {
        #pragma unroll
        for (int nb = 0; nb < 2; ++nb) {
            const int n = 32 * w + nb * 16 + ml;
            const int k0 = kb * 32 + quad * 8;
            #pragma unroll
            for (int j = 0; j < 8; ++j)
                Bf[kb][nb][j] = (short)f2bf(W[(k0 + j) * F + n]);
        }
    }

    const int nTiles = NN / 32;                     // 3125
    for (int tile = gid; tile < nTiles; tile += 384) {
        const int row0 = tile * 32;
        __syncthreads();
        // stage A tile in fragment order: 512 chunks of 8 floats -> bf16
        #pragma unroll
        for (int c = 0; c < 2; ++c) {
            const int i2 = tid + 256 * c;           // 0..511
            const int m  = i2 >> 4;                 // row 0..31
            const int o  = i2 & 15;                 // k-octet
            const float* xr = &in[(size_t)(row0 + m) * F + o * 8];
            const float4 v0 = *(const float4*)xr;
            const float4 v1 = *(const float4*)(xr + 4);
            short h8[8];
            h8[0] = (short)f2bf(v0.x); h8[1] = (short)f2bf(v0.y);
            h8[2] = (short)f2bf(v0.z); h8[3] = (short)f2bf(v0.w);
            h8[4] = (short)f2bf(v1.x); h8[5] = (short)f2bf(v1.y);
            h8[6] = (short)f2bf(v1.z); h8[7] = (short)f2bf(v1.w);
            const int kb2 = o >> 2, q2 = o & 3, ml2 = m & 15, mh2 = m >> 4;
            const int fo = (((mh2 * 4 + kb2) * 64) + q2 * 16 + ml2) * 16;
            *(bf16x8*)(A_s + fo) = *(bf16x8*)h8;
        }
        __syncthreads();

        f32x4 acc00 = {0,0,0,0}, acc01 = {0,0,0,0}, acc10 = {0,0,0,0}, acc11 = {0,0,0,0};
        #pragma unroll
        for (int kb = 0; kb < 4; ++kb) {
            const bf16x8 ah0 = *(const bf16x8*)(A_s + (kb * 64 + lane) * 16);
            const bf16x8 ah1 = *(const bf16x8*)(A_s + ((4 + kb) * 64 + lane) * 16);
            acc00 = __builtin_amdgcn_mfma_f32_16x16x32_bf16(ah0, Bf[kb][0], acc00, 0, 0, 0);
            acc01 = __builtin_amdgcn_mfma_f32_16x16x32_bf16(ah0, Bf[kb][1], acc01, 0, 0, 0);
            acc10 = __builtin_amdgcn_mfma_f32_16x16x32_bf16(ah1, Bf[kb][0], acc10, 0, 0, 0);
            acc11 = __builtin_amdgcn_mfma_f32_16x16x32_bf16(ah1, Bf[kb][1], acc11, 0, 0, 0);
        }

        // epilogue: C/D layout col=lane&15, row=quad*4+reg
        #pragma unroll
        for (int mh = 0; mh < 2; ++mh) {
            #pragma unroll
            for (int nb = 0; nb < 2; ++nb) {
                const f32x4 a = (mh == 0) ? (nb == 0 ? acc00 : acc01)
                                          : (nb == 0 ? acc10 : acc11);
                const int row = row0 + mh * 16 + quad * 4;
                const int col = 32 * w + nb * 16 + ml;
                #pragma unroll
                for (int r = 0; r < 4; ++r)
                    out_bf[(size_t)(row + r) * F + col] = f2bf(a[r]);
            }
        }
    }
}

// ---------------- pass 2: region -> fine buckets; + per-region deg histogram ----------------
// grid = 49 regions x 17: j<16 sort a region slice into 64 fine buckets (coalesced);
// j==16: LDS-histogram the region's src stream -> norm_src (replaces global atomics).
__global__ __launch_bounds__(256)
void pass2_kernel(const int* __restrict__ gRegion, const unsigned short* __restrict__ gRegionS,
                  const int* __restrict__ gRegCur, const int* __restrict__ gRegCurS,
                  int* __restrict__ gCur, int* __restrict__ srcPart,
                  float* __restrict__ norm_src) {
    __shared__ __align__(16) char smem[12544];

    const int r   = blockIdx.x / P2J;
    const int j   = blockIdx.x % P2J;
    const int tid = threadIdx.x;

    if (j == P2SPLIT) {                       // ---- deg role: src histogram
        int* hist = (int*)smem;               // 2048 ints
        const int total = min(gRegCurS[r * GSTRIDE] - r * RCAP, RCAP);
        for (int t = tid; t < 2048; t += 256) hist[t] = 0;
        __syncthreads();
        for (int i = tid; i < total; i += 256)
            atomicAdd(&hist[gRegionS[r * RCAP + i]], 1);
        __syncthreads();
        const int nlo = r * 2048;
        for (int t = tid; t < 2048; t += 256) {
            const int n = nlo + t;
            if (n < NN) norm_src[n] = rsqrtf((float)max(hist[t], 1));
        }
        return;
    }

    // ---- sort role
    int* sortedL = (int*)smem;                              // P2MAX ints (9216 B)
    unsigned char* fbOf = (unsigned char*)(smem + 9216);    // P2MAX u8 (2304 B)
    int* cnt  = (int*)(smem + 11520);                       // 64 ints
    int* cur  = cnt + 64;
    int* base = cur + 64;

    const int total = min(gRegCur[r * GSTRIDE] - r * RCAP, RCAP);
    const int per = (total + P2SPLIT - 1) / P2SPLIT;
    const int i0 = j * per;
    const int i1 = min(total, i0 + per);
    const int n = i1 - i0;                       // may be <= 0 for tail blocks

    if (tid < 64) cnt[tid] = 0;
    __syncthreads();

    int v[9];                                    // ceil(P2MAX/256) = 9
    #pragma unroll
    for (int k = 0; k < 9; ++k) {
        const int i = tid + k * 256;
        if (i < n) {
            const int vv = gRegion[r * RCAP + i0 + i];
            v[k] = vv;
            atomicAdd(&cnt[vv >> 22], 1);        // fb = (d&0x7FF)>>5
        }
    }
    __syncthreads();
    if (tid < 64 && cnt[tid] > 0)
        base[tid] = atomicAdd(&gCur[(r * 64 + tid) * GSTRIDE], cnt[tid]);
    if (tid == 0) {
        int run = 0;
        for (int f = 0; f < 64; ++f) { cur[f] = run; run += cnt[f]; }
    }
    __syncthreads();
    #pragma unroll
    for (int k = 0; k < 9; ++k) {
        const int i = tid + k * 256;
        if (i < n) {
            const int fb = v[k] >> 22;
            const int p = atomicAdd(&cur[fb], 1);
            sortedL[p] = v[k] & 0x3FFFFF;        // s | ((d&31)<<17)
            fbOf[p] = (unsigned char)fb;
        }
    }
    __syncthreads();
    for (int i = tid; i < n; i += 256) {
        const int fb = fbOf[i];
        const int dstAbs = base[fb] + (i - (cur[fb] - cnt[fb]));
        if (dstAbs < (r * 64 + fb + 1) * BCAPG)
            srcPart[dstAbs] = sortedL[i];
    }
}

// ---------------- gather + per-bucket LDS counting sort + fused layer-2 head fold ----------------
// Round-9 proven: single-node gather loop (VGPR ~48) + wave-0 register scan.
__global__ __launch_bounds__(256)
void gather_sort_kernel(const unsigned short* __restrict__ hs,
                        int* __restrict__ srcPart, const int* __restrict__ gCur,
                        const float* __restrict__ norm_src, const float* __restrict__ bias,
                        const float2* __restrict__ V, float2* __restrict__ uw,
                        int* __restrict__ offs, int* __restrict__ ends,
                        float* __restrict__ norm_dst) {
    __shared__ int cnt[32];
    __shared__ int loc[32];       // inclusive prefix
    __shared__ int cur[32];
    __shared__ int sortedL[BCAPG];

    const int b   = blockIdx.x;
    const int tid = threadIdx.x;
    const int nlo = b * 32;                      // NN == NBUCK*32 exactly
    const int eBase = b * BCAPG;
    const int total = min(gCur[b * GSTRIDE] - eBase, BCAPG);

    if (tid < 32) cnt[tid] = 0;
    __syncthreads();
    for (int i = tid; i < total; i += 256)
        atomicAdd(&cnt[(srcPart[eBase + i] >> 17) & 31], 1);
    __syncthreads();
    if (tid < 64) {                              // wave-0 register prefix scan
        const int l32 = tid & 31;
        const int c = cnt[l32];
        int v = c;
        #pragma unroll
        for (int off = 1; off < 32; off <<= 1) {
            const int t = __shfl_up(v, off, 32);
            if (l32 >= off) v += t;
        }
        if (tid < 32) {
            loc[tid] = v;                        // inclusive prefix
            cur[tid] = v - c;
            const int st = eBase + v - c;
            offs[nlo + tid] = st;
            ends[nlo + tid] = st + c;
            norm_dst[nlo + tid] = rsqrtf((float)max(c, 1));
        }
    }
    __syncthreads();
    for (int i = tid; i < total; i += 256) {
        const int v = srcPart[eBase + i];
        const int r = atomicAdd(&cur[(v >> 17) & 31], 1);
        sortedL[r] = v & 0x1FFFF;
    }
    __syncthreads();
    // coalesced write of sorted src ids (for ac_kernel)
    for (int i = tid; i < total; i += 256)
        srcPart[eBase + i] = sortedL[i];

    // ---- feature gather (per wave: 8 nodes; 16 lanes per edge, 8 bf16 cols/lane)
    const int w  = tid >> 6;
    const int l  = tid & 63;
    const int q  = l >> 4;
    const int c8 = (l & 15) * 8;
    float bb[8];
    *(float4*)&bb[0] = *(const float4*)&bias[c8];
    *(float4*)&bb[4] = *(const float4*)&bias[c8 + 4];
    float2 Vl[8];
    #pragma unroll
    for (int k = 0; k < 8; ++k) Vl[k] = V[c8 + k];

    const int nhEnd = (w + 1) * 8;
    for (int nh = w * 8; nh < nhEnd; ++nh) {
        const int end = loc[nh];
        const int beg = end - cnt[nh];
        float acc[8] = {0.f, 0.f, 0.f, 0.f, 0.f, 0.f, 0.f, 0.f};
        int j = beg;
        for (; j + 16 <= end; j += 16) {      // 16 edges in flight per wave
            const int s0 = sortedL[j + q];
            const int s1 = sortedL[j + 4 + q];
            const int s2 = sortedL[j + 8 + q];
            const int s3 = sortedL[j + 12 + q];
            const float ns0 = norm_src[s0];
            const float ns1 = norm_src[s1];
            const float ns2 = norm_src[s2];
            const float ns3 = norm_src[s3];
            const uint4 v0 = *(const uint4*)&hs[(size_t)s0 * F + c8];
            const uint4 v1 = *(const uint4*)&hs[(size_t)s1 * F + c8];
            const uint4 v2 = *(const uint4*)&hs[(size_t)s2 * F + c8];
            const uint4 v3 = *(const uint4*)&hs[(size_t)s3 * F + c8];
            acc_bf8s(v0, ns0, acc);
            acc_bf8s(v1, ns1, acc);
            acc_bf8s(v2, ns2, acc);
            acc_bf8s(v3, ns3, acc);
        }
        for (; j + 8 <= end; j += 8) {
            const int s0 = sortedL[j + q];
            const int s1 = sortedL[j + 4 + q];
            const float ns0 = norm_src[s0];
            const float ns1 = norm_src[s1];
            const uint4 v0 = *(const uint4*)&hs[(size_t)s0 * F + c8];
            const uint4 v1 = *(const uint4*)&hs[(size_t)s1 * F + c8];
            acc_bf8s(v0, ns0, acc);
            acc_bf8s(v1, ns1, acc);
        }
        for (; j + 4 <= end; j += 4) {
            const int s = sortedL[j + q];
            const float ns = norm_src[s];
            const uint4 v = *(const uint4*)&hs[(size_t)s * F + c8];
            acc_bf8s(v, ns, acc);
        }
        if (j + q < end) {
            const int s = sortedL[j + q];
            const float ns = norm_src[s];
            const uint4 v = *(const uint4*)&hs[(size_t)s * F + c8];
            acc_bf8s(v, ns, acc);
        }
        #pragma unroll
        for (int k = 0; k < 8; ++k) {
            acc[k] += __shfl_xor(acc[k], 16);
            acc[k] += __shfl_xor(acc[k], 32);
        }

        const int n = nlo + nh;
        const float nd = rsqrtf((float)max(cnt[nh], 1));
        float pa = 0.f, pc = 0.f;
        #pragma unroll
        for (int k = 0; k < 8; ++k) {
            const float ok = fmaxf(acc[k] * nd + bb[k], 0.f);
            pa += ok * Vl[k].x;
            pc += ok * Vl[k].y;
        }
        #pragma unroll
        for (int m = 1; m <= 8; m <<= 1) {
            pa += __shfl_xor(pa, m);
            pc += __shfl_xor(pc, m);
        }
        if (l == 0) {
            const float ns = norm_src[n];
            uw[n] = make_float2(ns * pa, ns * pc);
        }
    }
}

// ---------------- layer-2 aggregation: bucket-parallel (8 threads/node) ----------------
__global__ __launch_bounds__(256, 8)
void ac_kernel(const float2* __restrict__ uw, const int* __restrict__ sorted_src,
               const int* __restrict__ offs, const int* __restrict__ ends,
               const float* __restrict__ norm_dst,
               float* __restrict__ A, float* __restrict__ C) {
    const int tid = threadIdx.x;
    const int n   = blockIdx.x * 32 + (tid >> 3);   // NN == NBUCK*32 exactly
    const int sub = tid & 7;
    const int beg = offs[n];
    const int end = ends[n];
    float sx = 0.f, sy = 0.f;
    for (int j = beg + sub; j < end; j += 8) {
        const float2 t = uw[sorted_src[j]];
        sx += t.x;
        sy += t.y;
    }
    sx += __shfl_xor(sx, 1); sy += __shfl_xor(sy, 1);
    sx += __shfl_xor(sx, 2); sy += __shfl_xor(sy, 2);
    sx += __shfl_xor(sx, 4); sy += __shfl_xor(sy, 4);
    if (sub == 0) {
        const float nd = norm_dst[n];
        A[n] = nd * sx;
        C[n] = nd * sy;
    }
}

// ---------------- edge scores (4-wide) ----------------
__global__ void score_kernel(const float* __restrict__ A, const float* __restrict__ C,
                             const int4* __restrict__ src4, const int4* __restrict__ dst4,
                             const float* __restrict__ consts, float4* __restrict__ out4,
                             int nE4) {
    const int i = blockIdx.x * blockDim.x + threadIdx.x;
    if (i < nE4) {
        const int4 s = src4[i];
        const int4 d = dst4[i];
        const float cc = consts[0];
        float4 o;
        o.x = 1.f / (1.f + __expf(-(A[s.x] + C[d.x] + cc)));
        o.y = 1.f / (1.f + __expf(-(A[s.y] + C[d.y] + cc)));
        o.z = 1.f / (1.f + __expf(-(A[s.z] + C[d.z] + cc)));
        o.w = 1.f / (1.f + __expf(-(A[s.w] + C[d.w] + cc)));
        out4[i] = o;
    }
}

extern "C" void kernel_launch(void* const* d_in, const int* in_sizes, int n_in,
                              void* d_out, int out_size, void* d_ws, size_t ws_size,
                              hipStream_t stream) {
    const float* x  = (const float*)d_in[0];
    const float* W1 = (const float*)d_in[1];
    const float* b1 = (const float*)d_in[2];
    const float* W2 = (const float*)d_in[3];
    const float* b2 = (const float*)d_in[4];
    const float* Wp = (const float*)d_in[5];
    const float* bp = (const float*)d_in[6];
    const int*   src = (const int*)d_in[7];
    const int*   dst = (const int*)d_in[8];
    float* out = (float*)d_out;

    float* ws        = (float*)d_ws;
    float* norm_src  = ws;                        // NPAD
    float* bufA      = ws + NPAD;                 // NPAD: A[]
    float* bufC      = ws + 2 * NPAD;             // NPAD: C[]
    float* norm_dst  = ws + 3 * NPAD;             // NPAD
    int*   offs      = (int*)(ws + 4 * NPAD);     // NPAD
    int*   ends      = offs + NPAD;               // NPAD
    int*   gCur      = ends + NPAD;               // NBUCK*GSTRIDE = 50000, pad 50176
    int*   gRegCur   = gCur + 50176;              // NREG*GSTRIDE = 784, pad 1024
    int*   gRegCurS  = gRegCur + 1024;            // NREG*GSTRIDE = 784, pad 1024
    float* consts    = (float*)(gRegCurS + 1024); // 16
    float2* V        = (float2*)(consts + 16);    // 128 float2
    float2* uw       = V + 128;                   // NN float2
    int*   srcPart   = (int*)(uw + NN);           // NBUCK*BCAPG ints (9.6 MB)
    unsigned short* hs_bf = (unsigned short*)(srcPart + (size_t)NBUCK * BCAPG);  // NN*F bf16
    int*   gRegion   = (int*)(hs_bf + (size_t)NN * F);          // NREG*RCAP ints (7.2 MB)
    unsigned short* gRegionS = (unsigned short*)(gRegion + (size_t)NREG * RCAP); // NREG*RCAP u16 (3.6 MB)

    // cursors + folded head weights
    setup_kernel<<<15, 256, 0, stream>>>(gCur, gRegCur, gRegCurS, W2, Wp, b2, bp, consts, V);

    // layer-1 MFMA GEMM overlapped with dual-stream coarse binning (no global atomics)
    gemm1_fill_kernel<<<768, 256, 0, stream>>>(x, W1, hs_bf, src, dst,
                                               gRegCur, gRegCurS, gRegion, gRegionS);

    // pass 2: regions -> fine 32-node buckets (coalesced) + per-region deg histogram -> norm_src
    pass2_kernel<<<NREG * P2J, 256, 0, stream>>>(gRegion, gRegionS, gRegCur, gRegCurS,
                                                 gCur, srcPart, norm_src);

    // per-bucket LDS sort + feature gather + folded layer-2 head
    gather_sort_kernel<<<NBUCK, 256, 0, stream>>>(hs_bf, srcPart, gCur, norm_src, b1,
                                                  V, uw, offs, ends, norm_dst);

    // layer-2 aggregation: bucket-parallel, 8 threads per node
    ac_kernel<<<NBUCK, 256, 0, stream>>>(uw, srcPart, offs, ends, norm_dst,
                                         bufA, bufC);

    // edge scores (NE divisible by 4)
    score_kernel<<<(NE / 4 + 255) / 256, 256, 0, stream>>>(bufA, bufC, (const int4*)src,
                                                           (const int4*)dst, consts,
                                                           (float4*)out, NE / 4);
}

// Round 11
// 283.406 us; speedup vs baseline: 1.2064x; 1.0058x over previous
//
#include <hip/hip_runtime.h>
#include <cstdint>
#include <cstddef>

#define NN 100000
#define NE 1600000
#define F  128
#define NPAD 100352          // 98 * 1024
#define NBUCK 3125           // NN / 32 fine buckets of 32 nodes (gather granularity)
#define BCAPG 768            // fine bucket capacity (mean 512, +11 sd)
#define CHUNK 3125           // NE / 512 fill chunks (exact)
#define GSTRIDE 16           // cursor padding: one counter per 64B line
#define NREG 49              // coarse regions (2048 nodes each)
#define RCAP 36864           // region capacity (mean ~32650, +23 sd)
#define P2SPLIT 16           // pass-2 sort blocks per region
#define P2J 17               // + 1 deg-histogram block per region
#define P2MAX 2304           // ceil(RCAP / P2SPLIT)

typedef __attribute__((ext_vector_type(8))) short bf16x8;
typedef __attribute__((ext_vector_type(4))) float f32x4;

// bf16 helpers (RNE)
__device__ __forceinline__ unsigned short f2bf(float f) {
    unsigned u = __float_as_uint(f);
    unsigned r = (u + 0x7fffu + ((u >> 16) & 1u)) >> 16;
    return (unsigned short)r;
}
__device__ __forceinline__ void acc_bf8s(const uint4 v, const float ns, float* acc) {
    acc[0] += __uint_as_float(v.x << 16) * ns;
    acc[1] += __uint_as_float(v.x & 0xffff0000u) * ns;
    acc[2] += __uint_as_float(v.y << 16) * ns;
    acc[3] += __uint_as_float(v.y & 0xffff0000u) * ns;
    acc[4] += __uint_as_float(v.z << 16) * ns;
    acc[5] += __uint_as_float(v.z & 0xffff0000u) * ns;
    acc[6] += __uint_as_float(v.w << 16) * ns;
    acc[7] += __uint_as_float(v.w & 0xffff0000u) * ns;
}

// ---------------- setup: cursors + head constant + V = W2 @ Wp ----------------
__global__ void setup_kernel(int* __restrict__ gCur, int* __restrict__ gRegCur,
                             int* __restrict__ gRegCurS,
                             const float* __restrict__ W2, const float* __restrict__ Wp,
                             const float* __restrict__ b2, const float* __restrict__ bp,
                             float* __restrict__ consts, float2* __restrict__ V) {
    const int g = blockIdx.x;
    const int tid = threadIdx.x;
    if (g < 13) {                         // 13*256 = 3328 >= NBUCK
        const int b = g * 256 + tid;
        if (b < NBUCK) gCur[b * GSTRIDE] = b * BCAPG;
        return;
    }
    if (g == 14) {                        // region cursors (both streams)
        if (tid < NREG) gRegCur[tid * GSTRIDE] = tid * RCAP;
        else if (tid >= 64 && tid < 64 + NREG) {
            const int r = tid - 64;
            gRegCurS[r * GSTRIDE] = r * RCAP;
        }
        return;
    }
    // block 13: head fold weights + constant
    if (tid < 128) {                      // V[i] = (W2[i]·Wp_a, W2[i]·Wp_c)
        float sa = 0.f, sc = 0.f;
        #pragma unroll 8
        for (int j = 0; j < F; ++j) {
            const float w = W2[tid * F + j];
            sa += w * Wp[j];
            sc += w * Wp[F + j];
        }
        V[tid] = make_float2(sa, sc);
    } else if (tid < 192) {               // wave 2: cc = b2.Wp_a + b2.Wp_c + bp
        const int l = tid - 128;
        const float2 bb = *(const float2*)&b2[2 * l];
        const float2 wa = *(const float2*)&Wp[2 * l];
        const float2 wc = *(const float2*)&Wp[F + 2 * l];
        float s = bb.x * (wa.x + wc.x) + bb.y * (wa.y + wc.y);
        #pragma unroll
        for (int m = 32; m > 0; m >>= 1) s += __shfl_xor(s, m);
        if (l == 0) consts[0] = s + bp[0];
    }
}

// ---------------- fused gemm1 (MFMA) + dual-stream coarse binning ----------------
// 1024 blocks, 4/CU fully resident (launch_bounds(256,4); VGPR 44 << 128 cap).
// blockIdx%2==1 -> fill role (512 blocks): TWO LDS counting sorts of a 3125-edge chunk:
//   round 1 by dst>>11 -> gRegion (packed s|(d&0x7FF)<<17), coalesced runs;
//   round 2 by src>>11 -> gRegionS (u16 s&0x7FF), coalesced runs.
//   ZERO per-edge global atomics (deg derived in pass2 by LDS histogram).
// blockIdx%2==0 -> gemm role (512 blocks): hs_bf = bf16(x @ W1), 32x128 MFMA tiles.
__global__ __launch_bounds__(256, 4)
void gemm1_fill_kernel(const float* __restrict__ in, const float* __restrict__ W,
                       unsigned short* __restrict__ out_bf,
                       const int* __restrict__ src, const int* __restrict__ dst,
                       int* __restrict__ gRegCur, int* __restrict__ gRegCurS,
                       int* __restrict__ gRegion, unsigned short* __restrict__ gRegionS) {
    __shared__ __align__(16) char smem[16448];

    const int g = blockIdx.x;
    const int tid = threadIdx.x;

    if (g & 1) {                                    // ---- fill role (512 blocks)
        int* sortedL = (int*)smem;                          // CHUNK ints   (12500 B)
        unsigned char* regOf = (unsigned char*)(sortedL + CHUNK);  // CHUNK u8 (3125 B)
        int* cnt  = (int*)(smem + 15628);                   // NREG ints
        int* cur  = cnt + NREG;                             // NREG ints
        int* base = cur + NREG;                             // NREG ints

        const int e0 = (g >> 1) * CHUNK;                    // 512 * 3125 == NE exactly
        const int nCh = CHUNK;

        // ---- round 1: key = dst >> 11
        if (tid < NREG) cnt[tid] = 0;
        __syncthreads();
        for (int i = tid; i < nCh; i += 256)
            atomicAdd(&cnt[dst[e0 + i] >> 11], 1);
        __syncthreads();
        if (tid < NREG && cnt[tid] > 0)
            base[tid] = atomicAdd(&gRegCur[tid * GSTRIDE], cnt[tid]);
        if (tid == 0) {
            int run = 0;
            for (int r = 0; r < NREG; ++r) { cur[r] = run; run += cnt[r]; }
        }
        __syncthreads();
        for (int i = tid; i < nCh; i += 256) {
            const int s = src[e0 + i];
            const int d = dst[e0 + i];
            const int r = d >> 11;
            const int p = atomicAdd(&cur[r], 1);
            sortedL[p] = s | ((d & 0x7FF) << 17);
            regOf[p] = (unsigned char)r;
        }
        __syncthreads();
        for (int i = tid; i < nCh; i += 256) {
            const int r = regOf[i];
            const int dstAbs = base[r] + (i - (cur[r] - cnt[r]));
            if (dstAbs < (r + 1) * RCAP)
                gRegion[dstAbs] = sortedL[i];
        }
        __syncthreads();

        // ---- round 2: key = src >> 11 (deg stream, u16 payload)
        if (tid < NREG) cnt[tid] = 0;
        __syncthreads();
        for (int i = tid; i < nCh; i += 256)
            atomicAdd(&cnt[src[e0 + i] >> 11], 1);
        __syncthreads();
        if (tid < NREG && cnt[tid] > 0)
            base[tid] = atomicAdd(&gRegCurS[tid * GSTRIDE], cnt[tid]);
        if (tid == 0) {
            int run = 0;
            for (int r = 0; r < NREG; ++r) { cur[r] = run; run += cnt[r]; }
        }
        __syncthreads();
        for (int i = tid; i < nCh; i += 256) {
            const int s = src[e0 + i];
            const int r = s >> 11;
            const int p = atomicAdd(&cur[r], 1);
            sortedL[p] = s;
            regOf[p] = (unsigned char)r;
        }
        __syncthreads();
        for (int i = tid; i < nCh; i += 256) {
            const int r = regOf[i];
            const int dstAbs = base[r] + (i - (cur[r] - cnt[r]));
            if (dstAbs < (r + 1) * RCAP)
                gRegionS[dstAbs] = (unsigned short)(sortedL[i] & 0x7FF);
        }
        return;
    }

    // ---- gemm role (512 blocks), tile = 32 rows x 128 cols, ~6 tiles each
    char* A_s = smem;                   // 8 KB fragment-ordered A tile (bf16)

    const int gid  = g >> 1;
    const int w    = tid >> 6;          // wave 0..3 -> cols 32w..32w+31
    const int lane = tid & 63;
    const int ml   = lane & 15;
    const int quad = lane >> 4;

    // preload B frags once: Bf[kb][nb], j: bf16(W[(kb*32+quad*8+j)*F + 32w+nb*16+ml])
    bf16x8 Bf[4][2];
    #pragma unroll
    for (int kb = 0; kb < 4; ++kb) {
        #pragma unroll
        for (int nb = 0; nb < 2; ++nb) {
            const int n = 32 * w + nb * 16 + ml;
            const int k0 = kb * 32 + quad * 8;
            #pragma unroll
            for (int j = 0; j < 8; ++j)
                Bf[kb][nb][j] = (short)f2bf(W[(k0 + j) * F + n]);
        }
    }

    const int nTiles = NN / 32;                     // 3125
    for (int tile = gid; tile < nTiles; tile += 512) {
        const int row0 = tile * 32;
        __syncthreads();
        // stage A tile in fragment order: 512 chunks of 8 floats -> bf16
        #pragma unroll
        for (int c = 0; c < 2; ++c) {
            const int i2 = tid + 256 * c;           // 0..511
            const int m  = i2 >> 4;                 // row 0..31
            const int o  = i2 & 15;                 // k-octet
            const float* xr = &in[(size_t)(row0 + m) * F + o * 8];
            const float4 v0 = *(const float4*)xr;
            const float4 v1 = *(const float4*)(xr + 4);
            short h8[8];
            h8[0] = (short)f2bf(v0.x); h8[1] = (short)f2bf(v0.y);
            h8[2] = (short)f2bf(v0.z); h8[3] = (short)f2bf(v0.w);
            h8[4] = (short)f2bf(v1.x); h8[5] = (short)f2bf(v1.y);
            h8[6] = (short)f2bf(v1.z); h8[7] = (short)f2bf(v1.w);
            const int kb2 = o >> 2, q2 = o & 3, ml2 = m & 15, mh2 = m >> 4;
            const int fo = (((mh2 * 4 + kb2) * 64) + q2 * 16 + ml2) * 16;
            *(bf16x8*)(A_s + fo) = *(bf16x8*)h8;
        }
        __syncthreads();

        f32x4 acc00 = {0,0,0,0}, acc01 = {0,0,0,0}, acc10 = {0,0,0,0}, acc11 = {0,0,0,0};
        #pragma unroll
        for (int kb = 0; kb < 4; ++kb) {
            const bf16x8 ah0 = *(const bf16x8*)(A_s + (kb * 64 + lane) * 16);
            const bf16x8 ah1 = *(const bf16x8*)(A_s + ((4 + kb) * 64 + lane) * 16);
            acc00 = __builtin_amdgcn_mfma_f32_16x16x32_bf16(ah0, Bf[kb][0], acc00, 0, 0, 0);
            acc01 = __builtin_amdgcn_mfma_f32_16x16x32_bf16(ah0, Bf[kb][1], acc01, 0, 0, 0);
            acc10 = __builtin_amdgcn_mfma_f32_16x16x32_bf16(ah1, Bf[kb][0], acc10, 0, 0, 0);
            acc11 = __builtin_amdgcn_mfma_f32_16x16x32_bf16(ah1, Bf[kb][1], acc11, 0, 0, 0);
        }

        // epilogue: C/D layout col=lane&15, row=quad*4+reg
        #pragma unroll
        for (int mh = 0; mh < 2; ++mh) {
            #pragma unroll
            for (int nb = 0; nb < 2; ++nb) {
                const f32x4 a = (mh == 0) ? (nb == 0 ? acc00 : acc01)
                                          : (nb == 0 ? acc10 : acc11);
                const int row = row0 + mh * 16 + quad * 4;
                const int col = 32 * w + nb * 16 + ml;
                #pragma unroll
                for (int r = 0; r < 4; ++r)
                    out_bf[(size_t)(row + r) * F + col] = f2bf(a[r]);
            }
        }
    }
}

// ---------------- pass 2: region -> fine buckets; + per-region deg histogram ----------------
__global__ __launch_bounds__(256)
void pass2_kernel(const int* __restrict__ gRegion, const unsigned short* __restrict__ gRegionS,
                  const int* __restrict__ gRegCur, const int* __restrict__ gRegCurS,
                  int* __restrict__ gCur, int* __restrict__ srcPart,
                  float* __restrict__ norm_src) {
    __shared__ __align__(16) char smem[12544];

    const int r   = blockIdx.x / P2J;
    const int j   = blockIdx.x % P2J;
    const int tid = threadIdx.x;

    if (j == P2SPLIT) {                       // ---- deg role: src histogram
        int* hist = (int*)smem;               // 2048 ints
        const int total = min(gRegCurS[r * GSTRIDE] - r * RCAP, RCAP);
        for (int t = tid; t < 2048; t += 256) hist[t] = 0;
        __syncthreads();
        for (int i = tid; i < total; i += 256)
            atomicAdd(&hist[gRegionS[r * RCAP + i]], 1);
        __syncthreads();
        const int nlo = r * 2048;
        for (int t = tid; t < 2048; t += 256) {
            const int n = nlo + t;
            if (n < NN) norm_src[n] = rsqrtf((float)max(hist[t], 1));
        }
        return;
    }

    // ---- sort role
    int* sortedL = (int*)smem;                              // P2MAX ints (9216 B)
    unsigned char* fbOf = (unsigned char*)(smem + 9216);    // P2MAX u8 (2304 B)
    int* cnt  = (int*)(smem + 11520);                       // 64 ints
    int* cur  = cnt + 64;
    int* base = cur + 64;

    const int total = min(gRegCur[r * GSTRIDE] - r * RCAP, RCAP);
    const int per = (total + P2SPLIT - 1) / P2SPLIT;
    const int i0 = j * per;
    const int i1 = min(total, i0 + per);
    const int n = i1 - i0;                       // may be <= 0 for tail blocks

    if (tid < 64) cnt[tid] = 0;
    __syncthreads();

    int v[9];                                    // ceil(P2MAX/256) = 9
    #pragma unroll
    for (int k = 0; k < 9; ++k) {
        const int i = tid + k * 256;
        if (i < n) {
            const int vv = gRegion[r * RCAP + i0 + i];
            v[k] = vv;
            atomicAdd(&cnt[vv >> 22], 1);        // fb = (d&0x7FF)>>5
        }
    }
    __syncthreads();
    if (tid < 64 && cnt[tid] > 0)
        base[tid] = atomicAdd(&gCur[(r * 64 + tid) * GSTRIDE], cnt[tid]);
    if (tid == 0) {
        int run = 0;
        for (int f = 0; f < 64; ++f) { cur[f] = run; run += cnt[f]; }
    }
    __syncthreads();
    #pragma unroll
    for (int k = 0; k < 9; ++k) {
        const int i = tid + k * 256;
        if (i < n) {
            const int fb = v[k] >> 22;
            const int p = atomicAdd(&cur[fb], 1);
            sortedL[p] = v[k] & 0x3FFFFF;        // s | ((d&31)<<17)
            fbOf[p] = (unsigned char)fb;
        }
    }
    __syncthreads();
    for (int i = tid; i < n; i += 256) {
        const int fb = fbOf[i];
        const int dstAbs = base[fb] + (i - (cur[fb] - cnt[fb]));
        if (dstAbs < (r * 64 + fb + 1) * BCAPG)
            srcPart[dstAbs] = sortedL[i];
    }
}

// ---------------- gather + per-bucket LDS counting sort + fused layer-2 head fold ----------------
// Round-9 proven structure + dynamic per-wave node assignment (LDS counter) to
// remove intra-block degree-imbalance tail.
__global__ __launch_bounds__(256)
void gather_sort_kernel(const unsigned short* __restrict__ hs,
                        int* __restrict__ srcPart, const int* __restrict__ gCur,
                        const float* __restrict__ norm_src, const float* __restrict__ bias,
                        const float2* __restrict__ V, float2* __restrict__ uw,
                        int* __restrict__ offs, int* __restrict__ ends,
                        float* __restrict__ norm_dst) {
    __shared__ int cnt[32];
    __shared__ int loc[32];       // inclusive prefix
    __shared__ int cur[32];
    __shared__ int nextNode;
    __shared__ int sortedL[BCAPG];

    const int b   = blockIdx.x;
    const int tid = threadIdx.x;
    const int nlo = b * 32;                      // NN == NBUCK*32 exactly
    const int eBase = b * BCAPG;
    const int total = min(gCur[b * GSTRIDE] - eBase, BCAPG);

    if (tid < 32) cnt[tid] = 0;
    if (tid == 0) nextNode = 0;
    __syncthreads();
    for (int i = tid; i < total; i += 256)
        atomicAdd(&cnt[(srcPart[eBase + i] >> 17) & 31], 1);
    __syncthreads();
    if (tid < 64) {                              // wave-0 register prefix scan
        const int l32 = tid & 31;
        const int c = cnt[l32];
        int v = c;
        #pragma unroll
        for (int off = 1; off < 32; off <<= 1) {
            const int t = __shfl_up(v, off, 32);
            if (l32 >= off) v += t;
        }
        if (tid < 32) {
            loc[tid] = v;                        // inclusive prefix
            cur[tid] = v - c;
            const int st = eBase + v - c;
            offs[nlo + tid] = st;
            ends[nlo + tid] = st + c;
            norm_dst[nlo + tid] = rsqrtf((float)max(c, 1));
        }
    }
    __syncthreads();
    for (int i = tid; i < total; i += 256) {
        const int v = srcPart[eBase + i];
        const int r = atomicAdd(&cur[(v >> 17) & 31], 1);
        sortedL[r] = v & 0x1FFFF;
    }
    __syncthreads();
    // coalesced write of sorted src ids (for ac_kernel)
    for (int i = tid; i < total; i += 256)
        srcPart[eBase + i] = sortedL[i];
    __syncthreads();

    // ---- feature gather (dynamic: waves pull nodes; 16 lanes/edge, 8 bf16 cols/lane)
    const int l  = tid & 63;
    const int q  = l >> 4;
    const int c8 = (l & 15) * 8;
    float bb[8];
    *(float4*)&bb[0] = *(const float4*)&bias[c8];
    *(float4*)&bb[4] = *(const float4*)&bias[c8 + 4];
    float2 Vl[8];
    #pragma unroll
    for (int k = 0; k < 8; ++k) Vl[k] = V[c8 + k];

    for (;;) {
        int nh;
        if (l == 0) nh = atomicAdd(&nextNode, 1);
        nh = __shfl(nh, 0);
        if (nh >= 32) break;

        const int end = loc[nh];
        const int beg = end - cnt[nh];
        float acc[8] = {0.f, 0.f, 0.f, 0.f, 0.f, 0.f, 0.f, 0.f};
        int j = beg;
        for (; j + 16 <= end; j += 16) {      // 16 edges in flight per wave
            const int s0 = sortedL[j + q];
            const int s1 = sortedL[j + 4 + q];
            const int s2 = sortedL[j + 8 + q];
            const int s3 = sortedL[j + 12 + q];
            const float ns0 = norm_src[s0];
            const float ns1 = norm_src[s1];
            const float ns2 = norm_src[s2];
            const float ns3 = norm_src[s3];
            const uint4 v0 = *(const uint4*)&hs[(size_t)s0 * F + c8];
            const uint4 v1 = *(const uint4*)&hs[(size_t)s1 * F + c8];
            const uint4 v2 = *(const uint4*)&hs[(size_t)s2 * F + c8];
            const uint4 v3 = *(const uint4*)&hs[(size_t)s3 * F + c8];
            acc_bf8s(v0, ns0, acc);
            acc_bf8s(v1, ns1, acc);
            acc_bf8s(v2, ns2, acc);
            acc_bf8s(v3, ns3, acc);
        }
        for (; j + 8 <= end; j += 8) {
            const int s0 = sortedL[j + q];
            const int s1 = sortedL[j + 4 + q];
            const float ns0 = norm_src[s0];
            const float ns1 = norm_src[s1];
            const uint4 v0 = *(const uint4*)&hs[(size_t)s0 * F + c8];
            const uint4 v1 = *(const uint4*)&hs[(size_t)s1 * F + c8];
            acc_bf8s(v0, ns0, acc);
            acc_bf8s(v1, ns1, acc);
        }
        for (; j + 4 <= end; j += 4) {
            const int s = sortedL[j + q];
            const float ns = norm_src[s];
            const uint4 v = *(const uint4*)&hs[(size_t)s * F + c8];
            acc_bf8s(v, ns, acc);
        }
        if (j + q < end) {
            const int s = sortedL[j + q];
            const float ns = norm_src[s];
            const uint4 v = *(const uint4*)&hs[(size_t)s * F + c8];
            acc_bf8s(v, ns, acc);
        }
        #pragma unroll
        for (int k = 0; k < 8; ++k) {
            acc[k] += __shfl_xor(acc[k], 16);
            acc[k] += __shfl_xor(acc[k], 32);
        }

        const int n = nlo + nh;
        const float nd = rsqrtf((float)max(cnt[nh], 1));
        float pa = 0.f, pc = 0.f;
        #pragma unroll
        for (int k = 0; k < 8; ++k) {
            const float ok = fmaxf(acc[k] * nd + bb[k], 0.f);
            pa += ok * Vl[k].x;
            pc += ok * Vl[k].y;
        }
        #pragma unroll
        for (int m = 1; m <= 8; m <<= 1) {
            pa += __shfl_xor(pa, m);
            pc += __shfl_xor(pc, m);
        }
        if (l == 0) {
            const float ns = norm_src[n];
            uw[n] = make_float2(ns * pa, ns * pc);
        }
    }
}

// ---------------- layer-2 aggregation: bucket-parallel (8 threads/node) ----------------
__global__ __launch_bounds__(256, 8)
void ac_kernel(const float2* __restrict__ uw, const int* __restrict__ sorted_src,
               const int* __restrict__ offs, const int* __restrict__ ends,
               const float* __restrict__ norm_dst,
               float* __restrict__ A, float* __restrict__ C) {
    const int tid = threadIdx.x;
    const int n   = blockIdx.x * 32 + (tid >> 3);   // NN == NBUCK*32 exactly
    const int sub = tid & 7;
    const int beg = offs[n];
    const int end = ends[n];
    float sx = 0.f, sy = 0.f;
    for (int j = beg + sub; j < end; j += 8) {
        const float2 t = uw[sorted_src[j]];
        sx += t.x;
        sy += t.y;
    }
    sx += __shfl_xor(sx, 1); sy += __shfl_xor(sy, 1);
    sx += __shfl_xor(sx, 2); sy += __shfl_xor(sy, 2);
    sx += __shfl_xor(sx, 4); sy += __shfl_xor(sy, 4);
    if (sub == 0) {
        const float nd = norm_dst[n];
        A[n] = nd * sx;
        C[n] = nd * sy;
    }
}

// ---------------- edge scores (4-wide) ----------------
__global__ void score_kernel(const float* __restrict__ A, const float* __restrict__ C,
                             const int4* __restrict__ src4, const int4* __restrict__ dst4,
                             const float* __restrict__ consts, float4* __restrict__ out4,
                             int nE4) {
    const int i = blockIdx.x * blockDim.x + threadIdx.x;
    if (i < nE4) {
        const int4 s = src4[i];
        const int4 d = dst4[i];
        const float cc = consts[0];
        float4 o;
        o.x = 1.f / (1.f + __expf(-(A[s.x] + C[d.x] + cc)));
        o.y = 1.f / (1.f + __expf(-(A[s.y] + C[d.y] + cc)));
        o.z = 1.f / (1.f + __expf(-(A[s.z] + C[d.z] + cc)));
        o.w = 1.f / (1.f + __expf(-(A[s.w] + C[d.w] + cc)));
        out4[i] = o;
    }
}

extern "C" void kernel_launch(void* const* d_in, const int* in_sizes, int n_in,
                              void* d_out, int out_size, void* d_ws, size_t ws_size,
                              hipStream_t stream) {
    const float* x  = (const float*)d_in[0];
    const float* W1 = (const float*)d_in[1];
    const float* b1 = (const float*)d_in[2];
    const float* W2 = (const float*)d_in[3];
    const float* b2 = (const float*)d_in[4];
    const float* Wp = (const float*)d_in[5];
    const float* bp = (const float*)d_in[6];
    const int*   src = (const int*)d_in[7];
    const int*   dst = (const int*)d_in[8];
    float* out = (float*)d_out;

    float* ws        = (float*)d_ws;
    float* norm_src  = ws;                        // NPAD
    float* bufA      = ws + NPAD;                 // NPAD: A[]
    float* bufC      = ws + 2 * NPAD;             // NPAD: C[]
    float* norm_dst  = ws + 3 * NPAD;             // NPAD
    int*   offs      = (int*)(ws + 4 * NPAD);     // NPAD
    int*   ends      = offs + NPAD;               // NPAD
    int*   gCur      = ends + NPAD;               // NBUCK*GSTRIDE = 50000, pad 50176
    int*   gRegCur   = gCur + 50176;              // NREG*GSTRIDE = 784, pad 1024
    int*   gRegCurS  = gRegCur + 1024;            // NREG*GSTRIDE = 784, pad 1024
    float* consts    = (float*)(gRegCurS + 1024); // 16
    float2* V        = (float2*)(consts + 16);    // 128 float2
    float2* uw       = V + 128;                   // NN float2
    int*   srcPart   = (int*)(uw + NN);           // NBUCK*BCAPG ints (9.6 MB)
    unsigned short* hs_bf = (unsigned short*)(srcPart + (size_t)NBUCK * BCAPG);  // NN*F bf16
    int*   gRegion   = (int*)(hs_bf + (size_t)NN * F);          // NREG*RCAP ints (7.2 MB)
    unsigned short* gRegionS = (unsigned short*)(gRegion + (size_t)NREG * RCAP); // NREG*RCAP u16 (3.6 MB)

    // cursors + folded head weights
    setup_kernel<<<15, 256, 0, stream>>>(gCur, gRegCur, gRegCurS, W2, Wp, b2, bp, consts, V);

    // layer-1 MFMA GEMM overlapped with dual-stream coarse binning (no global atomics)
    gemm1_fill_kernel<<<1024, 256, 0, stream>>>(x, W1, hs_bf, src, dst,
                                                gRegCur, gRegCurS, gRegion, gRegionS);

    // pass 2: regions -> fine 32-node buckets (coalesced) + per-region deg histogram -> norm_src
    pass2_kernel<<<NREG * P2J, 256, 0, stream>>>(gRegion, gRegionS, gRegCur, gRegCurS,
                                                 gCur, srcPart, norm_src);

    // per-bucket LDS sort + feature gather + folded layer-2 head
    gather_sort_kernel<<<NBUCK, 256, 0, stream>>>(hs_bf, srcPart, gCur, norm_src, b1,
                                                  V, uw, offs, ends, norm_dst);

    // layer-2 aggregation: bucket-parallel, 8 threads per node
    ac_kernel<<<NBUCK, 256, 0, stream>>>(uw, srcPart, offs, ends, norm_dst,
                                         bufA, bufC);

    // edge scores (NE divisible by 4)
    score_kernel<<<(NE / 4 + 255) / 256, 256, 0, stream>>>(bufA, bufC, (const int4*)src,
                                                           (const int4*)dst, consts,
                                                           (float4*)out, NE / 4);
}

// Round 12
// 278.127 us; speedup vs baseline: 1.2293x; 1.0190x over previous
//
#include <hip/hip_runtime.h>
#include <cstdint>
#include <cstddef>

#define NN 100000
#define NE 1600000
#define F  128
#define NPAD 100352          // 98 * 1024
#define NBUCK 3125           // NN / 32 fine buckets of 32 nodes (gather granularity)
#define BCAPG 768            // fine bucket capacity (mean 512, +11 sd)
#define NFILL 768            // fill-role blocks
#define CHUNK 2084           // ceil(NE / NFILL)
#define NGEMM 768            // gemm-role blocks (grid 1536, 6/CU resident)
#define GSTRIDE 16           // cursor padding: one counter per 64B line
#define NREG 49              // coarse regions (2048 nodes each)
#define RCAP 36864           // region capacity (mean ~32650, +23 sd)
#define P2SPLIT 16           // pass-2 sort blocks per region
#define P2J 17               // + 1 deg-histogram block per region
#define P2MAX 2304           // ceil(RCAP / P2SPLIT)

typedef __attribute__((ext_vector_type(8))) short bf16x8;
typedef __attribute__((ext_vector_type(4))) float f32x4;

// bf16 helpers (RNE)
__device__ __forceinline__ unsigned short f2bf(float f) {
    unsigned u = __float_as_uint(f);
    unsigned r = (u + 0x7fffu + ((u >> 16) & 1u)) >> 16;
    return (unsigned short)r;
}
__device__ __forceinline__ void acc_bf8s(const uint4 v, const float ns, float* acc) {
    acc[0] += __uint_as_float(v.x << 16) * ns;
    acc[1] += __uint_as_float(v.x & 0xffff0000u) * ns;
    acc[2] += __uint_as_float(v.y << 16) * ns;
    acc[3] += __uint_as_float(v.y & 0xffff0000u) * ns;
    acc[4] += __uint_as_float(v.z << 16) * ns;
    acc[5] += __uint_as_float(v.z & 0xffff0000u) * ns;
    acc[6] += __uint_as_float(v.w << 16) * ns;
    acc[7] += __uint_as_float(v.w & 0xffff0000u) * ns;
}

// ---------------- setup: cursors + head constant + V = W2 @ Wp ----------------
__global__ void setup_kernel(int* __restrict__ gCur, int* __restrict__ gRegCur,
                             int* __restrict__ gRegCurS,
                             const float* __restrict__ W2, const float* __restrict__ Wp,
                             const float* __restrict__ b2, const float* __restrict__ bp,
                             float* __restrict__ consts, float2* __restrict__ V) {
    const int g = blockIdx.x;
    const int tid = threadIdx.x;
    if (g < 13) {                         // 13*256 = 3328 >= NBUCK
        const int b = g * 256 + tid;
        if (b < NBUCK) gCur[b * GSTRIDE] = b * BCAPG;
        return;
    }
    if (g == 14) {                        // region cursors (both streams)
        if (tid < NREG) gRegCur[tid * GSTRIDE] = tid * RCAP;
        else if (tid >= 64 && tid < 64 + NREG) {
            const int r = tid - 64;
            gRegCurS[r * GSTRIDE] = r * RCAP;
        }
        return;
    }
    // block 13: head fold weights + constant
    if (tid < 128) {                      // V[i] = (W2[i]·Wp_a, W2[i]·Wp_c)
        float sa = 0.f, sc = 0.f;
        #pragma unroll 8
        for (int j = 0; j < F; ++j) {
            const float w = W2[tid * F + j];
            sa += w * Wp[j];
            sc += w * Wp[F + j];
        }
        V[tid] = make_float2(sa, sc);
    } else if (tid < 192) {               // wave 2: cc = b2.Wp_a + b2.Wp_c + bp
        const int l = tid - 128;
        const float2 bb = *(const float2*)&b2[2 * l];
        const float2 wa = *(const float2*)&Wp[2 * l];
        const float2 wc = *(const float2*)&Wp[F + 2 * l];
        float s = bb.x * (wa.x + wc.x) + bb.y * (wa.y + wc.y);
        #pragma unroll
        for (int m = 32; m > 0; m >>= 1) s += __shfl_xor(s, m);
        if (l == 0) consts[0] = s + bp[0];
    }
}

// ---------------- fused gemm1 (MFMA) + dual-stream coarse binning (fused hist) ----------
// 1536 blocks, 6/CU fully resident (launch_bounds(256,6): VGPR cap 85 >= 44 needed).
// blockIdx%2==1 -> fill role (768 blocks, 2084-edge chunk):
//   ONE histogram pass computes both dst>>11 and src>>11 counts; both claims issue
//   from different waves; then place+copy-out per stream (staging buffer reused).
//   ZERO per-edge global atomics. smem 11.6 KB -> 6/CU fits (70 KB).
// blockIdx%2==0 -> gemm role (768 blocks): hs_bf = bf16(x @ W1), 32x128 MFMA tiles.
__global__ __launch_bounds__(256, 6)
void gemm1_fill_kernel(const float* __restrict__ in, const float* __restrict__ W,
                       unsigned short* __restrict__ out_bf,
                       const int* __restrict__ src, const int* __restrict__ dst,
                       int* __restrict__ gRegCur, int* __restrict__ gRegCurS,
                       int* __restrict__ gRegion, unsigned short* __restrict__ gRegionS) {
    __shared__ __align__(16) char smem[11616];

    const int g = blockIdx.x;
    const int tid = threadIdx.x;

    if (g & 1) {                                    // ---- fill role (768 blocks)
        int* sortedL = (int*)smem;                          // CHUNK ints (8336 B)
        unsigned char* regOf = (unsigned char*)(sortedL + CHUNK);  // CHUNK u8
        int* cntD  = (int*)(smem + 10424);                  // 6 x 49 ints
        int* curD  = cntD + NREG;
        int* baseD = curD + NREG;
        int* cntS  = baseD + NREG;
        int* curS  = cntS + NREG;
        int* baseS = curS + NREG;

        const int e0 = (g >> 1) * CHUNK;
        const int nCh = min(CHUNK, NE - e0);

        // ---- fused histogram pass (both keys)
        if (tid < NREG) { cntD[tid] = 0; cntS[tid] = 0; }
        __syncthreads();
        for (int i = tid; i < nCh; i += 256) {
            const int s = src[e0 + i];
            const int d = dst[e0 + i];
            atomicAdd(&cntD[d >> 11], 1);
            atomicAdd(&cntS[s >> 11], 1);
        }
        __syncthreads();
        if (tid < NREG && cntD[tid] > 0)
            baseD[tid] = atomicAdd(&gRegCur[tid * GSTRIDE], cntD[tid]);
        if (tid >= 64 && tid < 64 + NREG) {
            const int r = tid - 64;
            if (cntS[r] > 0)
                baseS[r] = atomicAdd(&gRegCurS[r * GSTRIDE], cntS[r]);
        }
        if (tid == 0) {
            int run = 0;
            for (int r = 0; r < NREG; ++r) { curD[r] = run; run += cntD[r]; }
        }
        if (tid == 64) {                    // different wave: runs in parallel
            int run = 0;
            for (int r = 0; r < NREG; ++r) { curS[r] = run; run += cntS[r]; }
        }
        __syncthreads();

        // ---- stream 1 (dst key): place + coalesced copy-out
        for (int i = tid; i < nCh; i += 256) {
            const int s = src[e0 + i];
            const int d = dst[e0 + i];
            const int r = d >> 11;
            const int p = atomicAdd(&curD[r], 1);
            sortedL[p] = s | ((d & 0x7FF) << 17);
            regOf[p] = (unsigned char)r;
        }
        __syncthreads();
        for (int i = tid; i < nCh; i += 256) {
            const int r = regOf[i];
            const int dstAbs = baseD[r] + (i - (curD[r] - cntD[r]));
            if (dstAbs < (r + 1) * RCAP)
                gRegion[dstAbs] = sortedL[i];
        }
        __syncthreads();

        // ---- stream 2 (src key): place + coalesced copy-out (u16)
        for (int i = tid; i < nCh; i += 256) {
            const int s = src[e0 + i];
            const int r = s >> 11;
            const int p = atomicAdd(&curS[r], 1);
            sortedL[p] = s;
            regOf[p] = (unsigned char)r;
        }
        __syncthreads();
        for (int i = tid; i < nCh; i += 256) {
            const int r = regOf[i];
            const int dstAbs = baseS[r] + (i - (curS[r] - cntS[r]));
            if (dstAbs < (r + 1) * RCAP)
                gRegionS[dstAbs] = (unsigned short)(sortedL[i] & 0x7FF);
        }
        return;
    }

    // ---- gemm role (768 blocks), tile = 32 rows x 128 cols, ~4 tiles each
    char* A_s = smem;                   // 8 KB fragment-ordered A tile (bf16)

    const int gid  = g >> 1;
    const int w    = tid >> 6;          // wave 0..3 -> cols 32w..32w+31
    const int lane = tid & 63;
    const int ml   = lane & 15;
    const int quad = lane >> 4;

    // preload B frags once: Bf[kb][nb], j: bf16(W[(kb*32+quad*8+j)*F + 32w+nb*16+ml])
    bf16x8 Bf[4][2];
    #pragma unroll
    for (int kb = 0; kb < 4; ++kb) {
        #pragma unroll
        for (int nb = 0; nb < 2; ++nb) {
            const int n = 32 * w + nb * 16 + ml;
            const int k0 = kb * 32 + quad * 8;
            #pragma unroll
            for (int j = 0; j < 8; ++j)
                Bf[kb][nb][j] = (short)f2bf(W[(k0 + j) * F + n]);
        }
    }

    const int nTiles = NN / 32;                     // 3125
    for (int tile = gid; tile < nTiles; tile += NGEMM) {
        const int row0 = tile * 32;
        __syncthreads();
        // stage A tile in fragment order: 512 chunks of 8 floats -> bf16
        #pragma unroll
        for (int c = 0; c < 2; ++c) {
            const int i2 = tid + 256 * c;           // 0..511
            const int m  = i2 >> 4;                 // row 0..31
            const int o  = i2 & 15;                 // k-octet
            const float* xr = &in[(size_t)(row0 + m) * F + o * 8];
            const float4 v0 = *(const float4*)xr;
            const float4 v1 = *(const float4*)(xr + 4);
            short h8[8];
            h8[0] = (short)f2bf(v0.x); h8[1] = (short)f2bf(v0.y);
            h8[2] = (short)f2bf(v0.z); h8[3] = (short)f2bf(v0.w);
            h8[4] = (short)f2bf(v1.x); h8[5] = (short)f2bf(v1.y);
            h8[6] = (short)f2bf(v1.z); h8[7] = (short)f2bf(v1.w);
            const int kb2 = o >> 2, q2 = o & 3, ml2 = m & 15, mh2 = m >> 4;
            const int fo = (((mh2 * 4 + kb2) * 64) + q2 * 16 + ml2) * 16;
            *(bf16x8*)(A_s + fo) = *(bf16x8*)h8;
        }
        __syncthreads();

        f32x4 acc00 = {0,0,0,0}, acc01 = {0,0,0,0}, acc10 = {0,0,0,0}, acc11 = {0,0,0,0};
        #pragma unroll
        for (int kb = 0; kb < 4; ++kb) {
            const bf16x8 ah0 = *(const bf16x8*)(A_s + (kb * 64 + lane) * 16);
            const bf16x8 ah1 = *(const bf16x8*)(A_s + ((4 + kb) * 64 + lane) * 16);
            acc00 = __builtin_amdgcn_mfma_f32_16x16x32_bf16(ah0, Bf[kb][0], acc00, 0, 0, 0);
            acc01 = __builtin_amdgcn_mfma_f32_16x16x32_bf16(ah0, Bf[kb][1], acc01, 0, 0, 0);
            acc10 = __builtin_amdgcn_mfma_f32_16x16x32_bf16(ah1, Bf[kb][0], acc10, 0, 0, 0);
            acc11 = __builtin_amdgcn_mfma_f32_16x16x32_bf16(ah1, Bf[kb][1], acc11, 0, 0, 0);
        }

        // epilogue: C/D layout col=lane&15, row=quad*4+reg
        #pragma unroll
        for (int mh = 0; mh < 2; ++mh) {
            #pragma unroll
            for (int nb = 0; nb < 2; ++nb) {
                const f32x4 a = (mh == 0) ? (nb == 0 ? acc00 : acc01)
                                          : (nb == 0 ? acc10 : acc11);
                const int row = row0 + mh * 16 + quad * 4;
                const int col = 32 * w + nb * 16 + ml;
                #pragma unroll
                for (int r = 0; r < 4; ++r)
                    out_bf[(size_t)(row + r) * F + col] = f2bf(a[r]);
            }
        }
    }
}

// ---------------- pass 2: region -> fine buckets; + per-region deg histogram ----------------
__global__ __launch_bounds__(256)
void pass2_kernel(const int* __restrict__ gRegion, const unsigned short* __restrict__ gRegionS,
                  const int* __restrict__ gRegCur, const int* __restrict__ gRegCurS,
                  int* __restrict__ gCur, int* __restrict__ srcPart,
                  float* __restrict__ norm_src) {
    __shared__ __align__(16) char smem[12544];

    const int r   = blockIdx.x / P2J;
    const int j   = blockIdx.x % P2J;
    const int tid = threadIdx.x;

    if (j == P2SPLIT) {                       // ---- deg role: src histogram
        int* hist = (int*)smem;               // 2048 ints
        const int total = min(gRegCurS[r * GSTRIDE] - r * RCAP, RCAP);
        for (int t = tid; t < 2048; t += 256) hist[t] = 0;
        __syncthreads();
        for (int i = tid; i < total; i += 256)
            atomicAdd(&hist[gRegionS[r * RCAP + i]], 1);
        __syncthreads();
        const int nlo = r * 2048;
        for (int t = tid; t < 2048; t += 256) {
            const int n = nlo + t;
            if (n < NN) norm_src[n] = rsqrtf((float)max(hist[t], 1));
        }
        return;
    }

    // ---- sort role
    int* sortedL = (int*)smem;                              // P2MAX ints (9216 B)
    unsigned char* fbOf = (unsigned char*)(smem + 9216);    // P2MAX u8 (2304 B)
    int* cnt  = (int*)(smem + 11520);                       // 64 ints
    int* cur  = cnt + 64;
    int* base = cur + 64;

    const int total = min(gRegCur[r * GSTRIDE] - r * RCAP, RCAP);
    const int per = (total + P2SPLIT - 1) / P2SPLIT;
    const int i0 = j * per;
    const int i1 = min(total, i0 + per);
    const int n = i1 - i0;                       // may be <= 0 for tail blocks

    if (tid < 64) cnt[tid] = 0;
    __syncthreads();

    int v[9];                                    // ceil(P2MAX/256) = 9
    #pragma unroll
    for (int k = 0; k < 9; ++k) {
        const int i = tid + k * 256;
        if (i < n) {
            const int vv = gRegion[r * RCAP + i0 + i];
            v[k] = vv;
            atomicAdd(&cnt[vv >> 22], 1);        // fb = (d&0x7FF)>>5
        }
    }
    __syncthreads();
    if (tid < 64 && cnt[tid] > 0)
        base[tid] = atomicAdd(&gCur[(r * 64 + tid) * GSTRIDE], cnt[tid]);
    if (tid == 0) {
        int run = 0;
        for (int f = 0; f < 64; ++f) { cur[f] = run; run += cnt[f]; }
    }
    __syncthreads();
    #pragma unroll
    for (int k = 0; k < 9; ++k) {
        const int i = tid + k * 256;
        if (i < n) {
            const int fb = v[k] >> 22;
            const int p = atomicAdd(&cur[fb], 1);
            sortedL[p] = v[k] & 0x3FFFFF;        // s | ((d&31)<<17)
            fbOf[p] = (unsigned char)fb;
        }
    }
    __syncthreads();
    for (int i = tid; i < n; i += 256) {
        const int fb = fbOf[i];
        const int dstAbs = base[fb] + (i - (cur[fb] - cnt[fb]));
        if (dstAbs < (r * 64 + fb + 1) * BCAPG)
            srcPart[dstAbs] = sortedL[i];
    }
}

// ---------------- gather + per-bucket LDS counting sort + fused layer-2 head fold ----------------
__global__ __launch_bounds__(256)
void gather_sort_kernel(const unsigned short* __restrict__ hs,
                        int* __restrict__ srcPart, const int* __restrict__ gCur,
                        const float* __restrict__ norm_src, const float* __restrict__ bias,
                        const float2* __restrict__ V, float2* __restrict__ uw,
                        int* __restrict__ offs, int* __restrict__ ends,
                        float* __restrict__ norm_dst) {
    __shared__ int cnt[32];
    __shared__ int loc[32];       // inclusive prefix
    __shared__ int cur[32];
    __shared__ int nextNode;
    __shared__ int sortedL[BCAPG];

    const int b   = blockIdx.x;
    const int tid = threadIdx.x;
    const int nlo = b * 32;                      // NN == NBUCK*32 exactly
    const int eBase = b * BCAPG;
    const int total = min(gCur[b * GSTRIDE] - eBase, BCAPG);

    if (tid < 32) cnt[tid] = 0;
    if (tid == 0) nextNode = 0;
    __syncthreads();
    for (int i = tid; i < total; i += 256)
        atomicAdd(&cnt[(srcPart[eBase + i] >> 17) & 31], 1);
    __syncthreads();
    if (tid < 64) {                              // wave-0 register prefix scan
        const int l32 = tid & 31;
        const int c = cnt[l32];
        int v = c;
        #pragma unroll
        for (int off = 1; off < 32; off <<= 1) {
            const int t = __shfl_up(v, off, 32);
            if (l32 >= off) v += t;
        }
        if (tid < 32) {
            loc[tid] = v;                        // inclusive prefix
            cur[tid] = v - c;
            const int st = eBase + v - c;
            offs[nlo + tid] = st;
            ends[nlo + tid] = st + c;
            norm_dst[nlo + tid] = rsqrtf((float)max(c, 1));
        }
    }
    __syncthreads();
    for (int i = tid; i < total; i += 256) {
        const int v = srcPart[eBase + i];
        const int r = atomicAdd(&cur[(v >> 17) & 31], 1);
        sortedL[r] = v & 0x1FFFF;
    }
    __syncthreads();
    // coalesced write of sorted src ids (for ac_kernel)
    for (int i = tid; i < total; i += 256)
        srcPart[eBase + i] = sortedL[i];
    __syncthreads();

    // ---- feature gather (dynamic: waves pull nodes; 16 lanes/edge, 8 bf16 cols/lane)
    const int l  = tid & 63;
    const int q  = l >> 4;
    const int c8 = (l & 15) * 8;
    float bb[8];
    *(float4*)&bb[0] = *(const float4*)&bias[c8];
    *(float4*)&bb[4] = *(const float4*)&bias[c8 + 4];
    float2 Vl[8];
    #pragma unroll
    for (int k = 0; k < 8; ++k) Vl[k] = V[c8 + k];

    for (;;) {
        int nh;
        if (l == 0) nh = atomicAdd(&nextNode, 1);
        nh = __shfl(nh, 0);
        if (nh >= 32) break;

        const int end = loc[nh];
        const int beg = end - cnt[nh];
        float acc[8] = {0.f, 0.f, 0.f, 0.f, 0.f, 0.f, 0.f, 0.f};
        int j = beg;
        for (; j + 16 <= end; j += 16) {      // 16 edges in flight per wave
            const int s0 = sortedL[j + q];
            const int s1 = sortedL[j + 4 + q];
            const int s2 = sortedL[j + 8 + q];
            const int s3 = sortedL[j + 12 + q];
            const float ns0 = norm_src[s0];
            const float ns1 = norm_src[s1];
            const float ns2 = norm_src[s2];
            const float ns3 = norm_src[s3];
            const uint4 v0 = *(const uint4*)&hs[(size_t)s0 * F + c8];
            const uint4 v1 = *(const uint4*)&hs[(size_t)s1 * F + c8];
            const uint4 v2 = *(const uint4*)&hs[(size_t)s2 * F + c8];
            const uint4 v3 = *(const uint4*)&hs[(size_t)s3 * F + c8];
            acc_bf8s(v0, ns0, acc);
            acc_bf8s(v1, ns1, acc);
            acc_bf8s(v2, ns2, acc);
            acc_bf8s(v3, ns3, acc);
        }
        for (; j + 8 <= end; j += 8) {
            const int s0 = sortedL[j + q];
            const int s1 = sortedL[j + 4 + q];
            const float ns0 = norm_src[s0];
            const float ns1 = norm_src[s1];
            const uint4 v0 = *(const uint4*)&hs[(size_t)s0 * F + c8];
            const uint4 v1 = *(const uint4*)&hs[(size_t)s1 * F + c8];
            acc_bf8s(v0, ns0, acc);
            acc_bf8s(v1, ns1, acc);
        }
        for (; j + 4 <= end; j += 4) {
            const int s = sortedL[j + q];
            const float ns = norm_src[s];
            const uint4 v = *(const uint4*)&hs[(size_t)s * F + c8];
            acc_bf8s(v, ns, acc);
        }
        if (j + q < end) {
            const int s = sortedL[j + q];
            const float ns = norm_src[s];
            const uint4 v = *(const uint4*)&hs[(size_t)s * F + c8];
            acc_bf8s(v, ns, acc);
        }
        #pragma unroll
        for (int k = 0; k < 8; ++k) {
            acc[k] += __shfl_xor(acc[k], 16);
            acc[k] += __shfl_xor(acc[k], 32);
        }

        const int n = nlo + nh;
        const float nd = rsqrtf((float)max(cnt[nh], 1));
        float pa = 0.f, pc = 0.f;
        #pragma unroll
        for (int k = 0; k < 8; ++k) {
            const float ok = fmaxf(acc[k] * nd + bb[k], 0.f);
            pa += ok * Vl[k].x;
            pc += ok * Vl[k].y;
        }
        #pragma unroll
        for (int m = 1; m <= 8; m <<= 1) {
            pa += __shfl_xor(pa, m);
            pc += __shfl_xor(pc, m);
        }
        if (l == 0) {
            const float ns = norm_src[n];
            uw[n] = make_float2(ns * pa, ns * pc);
        }
    }
}

// ---------------- layer-2 aggregation: bucket-parallel (8 threads/node) ----------------
__global__ __launch_bounds__(256, 8)
void ac_kernel(const float2* __restrict__ uw, const int* __restrict__ sorted_src,
               const int* __restrict__ offs, const int* __restrict__ ends,
               const float* __restrict__ norm_dst,
               float* __restrict__ A, float* __restrict__ C) {
    const int tid = threadIdx.x;
    const int n   = blockIdx.x * 32 + (tid >> 3);   // NN == NBUCK*32 exactly
    const int sub = tid & 7;
    const int beg = offs[n];
    const int end = ends[n];
    float sx = 0.f, sy = 0.f;
    for (int j = beg + sub; j < end; j += 8) {
        const float2 t = uw[sorted_src[j]];
        sx += t.x;
        sy += t.y;
    }
    sx += __shfl_xor(sx, 1); sy += __shfl_xor(sy, 1);
    sx += __shfl_xor(sx, 2); sy += __shfl_xor(sy, 2);
    sx += __shfl_xor(sx, 4); sy += __shfl_xor(sy, 4);
    if (sub == 0) {
        const float nd = norm_dst[n];
        A[n] = nd * sx;
        C[n] = nd * sy;
    }
}

// ---------------- edge scores (4-wide) ----------------
__global__ void score_kernel(const float* __restrict__ A, const float* __restrict__ C,
                             const int4* __restrict__ src4, const int4* __restrict__ dst4,
                             const float* __restrict__ consts, float4* __restrict__ out4,
                             int nE4) {
    const int i = blockIdx.x * blockDim.x + threadIdx.x;
    if (i < nE4) {
        const int4 s = src4[i];
        const int4 d = dst4[i];
        const float cc = consts[0];
        float4 o;
        o.x = 1.f / (1.f + __expf(-(A[s.x] + C[d.x] + cc)));
        o.y = 1.f / (1.f + __expf(-(A[s.y] + C[d.y] + cc)));
        o.z = 1.f / (1.f + __expf(-(A[s.z] + C[d.z] + cc)));
        o.w = 1.f / (1.f + __expf(-(A[s.w] + C[d.w] + cc)));
        out4[i] = o;
    }
}

extern "C" void kernel_launch(void* const* d_in, const int* in_sizes, int n_in,
                              void* d_out, int out_size, void* d_ws, size_t ws_size,
                              hipStream_t stream) {
    const float* x  = (const float*)d_in[0];
    const float* W1 = (const float*)d_in[1];
    const float* b1 = (const float*)d_in[2];
    const float* W2 = (const float*)d_in[3];
    const float* b2 = (const float*)d_in[4];
    const float* Wp = (const float*)d_in[5];
    const float* bp = (const float*)d_in[6];
    const int*   src = (const int*)d_in[7];
    const int*   dst = (const int*)d_in[8];
    float* out = (float*)d_out;

    float* ws        = (float*)d_ws;
    float* norm_src  = ws;                        // NPAD
    float* bufA      = ws + NPAD;                 // NPAD: A[]
    float* bufC      = ws + 2 * NPAD;             // NPAD: C[]
    float* norm_dst  = ws + 3 * NPAD;             // NPAD
    int*   offs      = (int*)(ws + 4 * NPAD);     // NPAD
    int*   ends      = offs + NPAD;               // NPAD
    int*   gCur      = ends + NPAD;               // NBUCK*GSTRIDE = 50000, pad 50176
    int*   gRegCur   = gCur + 50176;              // NREG*GSTRIDE = 784, pad 1024
    int*   gRegCurS  = gRegCur + 1024;            // NREG*GSTRIDE = 784, pad 1024
    float* consts    = (float*)(gRegCurS + 1024); // 16
    float2* V        = (float2*)(consts + 16);    // 128 float2
    float2* uw       = V + 128;                   // NN float2
    int*   srcPart   = (int*)(uw + NN);           // NBUCK*BCAPG ints (9.6 MB)
    unsigned short* hs_bf = (unsigned short*)(srcPart + (size_t)NBUCK * BCAPG);  // NN*F bf16
    int*   gRegion   = (int*)(hs_bf + (size_t)NN * F);          // NREG*RCAP ints (7.2 MB)
    unsigned short* gRegionS = (unsigned short*)(gRegion + (size_t)NREG * RCAP); // NREG*RCAP u16 (3.6 MB)

    // cursors + folded head weights
    setup_kernel<<<15, 256, 0, stream>>>(gCur, gRegCur, gRegCurS, W2, Wp, b2, bp, consts, V);

    // layer-1 MFMA GEMM overlapped with dual-stream coarse binning (no global atomics)
    gemm1_fill_kernel<<<NFILL + NGEMM, 256, 0, stream>>>(x, W1, hs_bf, src, dst,
                                                         gRegCur, gRegCurS, gRegion, gRegionS);

    // pass 2: regions -> fine 32-node buckets (coalesced) + per-region deg histogram -> norm_src
    pass2_kernel<<<NREG * P2J, 256, 0, stream>>>(gRegion, gRegionS, gRegCur, gRegCurS,
                                                 gCur, srcPart, norm_src);

    // per-bucket LDS sort + feature gather + folded layer-2 head
    gather_sort_kernel<<<NBUCK, 256, 0, stream>>>(hs_bf, srcPart, gCur, norm_src, b1,
                                                  V, uw, offs, ends, norm_dst);

    // layer-2 aggregation: bucket-parallel, 8 threads per node
    ac_kernel<<<NBUCK, 256, 0, stream>>>(uw, srcPart, offs, ends, norm_dst,
                                         bufA, bufC);

    // edge scores (NE divisible by 4)
    score_kernel<<<(NE / 4 + 255) / 256, 256, 0, stream>>>(bufA, bufC, (const int4*)src,
                                                           (const int4*)dst, consts,
                                                           (float4*)out, NE / 4);
}